// Round 18
// baseline (661.138 us; speedup 1.0000x reference)
//
#include <hip/hip_runtime.h>
#include <math.h>

#define BB 4
#define NNN 128
#define EMB 768
#define BIAF 200
#define HID 200
#define HHH 4
#define DHB 50
#define LLL 3
#define KKK 10
#define SS 3600
#define HSZ 402
#define CCC 200
#define NER 9

typedef short s16x8 __attribute__((ext_vector_type(8)));
typedef float f32x4 __attribute__((ext_vector_type(4)));

__device__ __forceinline__ ushort f2bf(float f) {
    union { float f; unsigned u; } c; c.f = f;
    unsigned u = c.u;
    return (ushort)((u + 0x7FFFu + ((u >> 16) & 1u)) >> 16);   // RNE
}
__device__ __forceinline__ float bf2f(ushort u) {
    union { unsigned u; float f; } c; c.u = ((unsigned)u) << 16; return c.f;
}
// 8x f32 -> bf16 fragment, pure C++ RNE (verified rounds 3-6; the
// v_cvt_pk_bf16_f32 asm variant FAILED correctness in round 7 — do not use)
__device__ __forceinline__ s16x8 cvt8(float4 f0, float4 f1) {
    s16x8 v;
    v[0]=(short)f2bf(f0.x); v[1]=(short)f2bf(f0.y); v[2]=(short)f2bf(f0.z); v[3]=(short)f2bf(f0.w);
    v[4]=(short)f2bf(f1.x); v[5]=(short)f2bf(f1.y); v[6]=(short)f2bf(f1.z); v[7]=(short)f2bf(f1.w);
    return v;
}

__device__ __forceinline__ float gelu_tanh(float x) {
    float x3 = x*x*x;
    return 0.5f*x*(1.0f + tanhf(0.79788456080286535588f*(x + 0.044715f*x3)));
}

// ======================= fused weight/input bf16 tiling =======================
__global__ void k_cvt_all(const float* __restrict__ word,
                          const float* __restrict__ Wh, const float* __restrict__ Wt,
                          const float* __restrict__ Wq, const float* __restrict__ Wk,
                          const float* __restrict__ Wv, const float* __restrict__ Wo,
                          const float* __restrict__ Wp, const float* __restrict__ Wb,
                          ushort* __restrict__ word_bf, ushort* __restrict__ whht_bf,
                          ushort* __restrict__ wall_bf, ushort* __restrict__ Wpt,
                          ushort* __restrict__ Wbt) {
    int gidx = blockIdx.x*256 + threadIdx.x;
    if (gidx < 393216) {
        int idx = gidx;
        int t = idx / 16384, r = idx % 16384;
        int c = r >> 3, j = r & 7;
        int kg = c / 512, row = c % 512;
        int k = t*32 + kg*8 + j;
        word_bf[idx] = f2bf(word[(size_t)row*EMB + k]);
    } else if (gidx < 712704) {
        int idx = gidx - 393216;
        int t = idx / 13312, r = idx % 13312;
        int c = r >> 3, j = r & 7;
        int kg = c / 416, n = c % 416;
        int k = t*32 + kg*8 + j;
        float v = 0.f;
        if (n < 200) v = Wh[k*200 + n];
        else if (n >= 208 && n < 408) v = Wt[k*200 + (n-208)];
        whht_bf[idx] = f2bf(v);
    } else if (gidx < 1271808) {
        int idx = gidx - 712704;
        int mat = idx / 46592, r = idx % 46592;
        int layer = mat >> 2, which = mat & 3;
        int t = r / 6656, r2 = r % 6656;
        int c = r2 >> 3, j = r2 & 7;
        int kg = c / 208, n = c % 208;
        int k = t*32 + kg*8 + j;
        float v = 0.f;
        if (k < 200 && n < 200) {
            const float* W = which == 0 ? Wq : (which == 1 ? Wk : (which == 2 ? Wv : Wo));
            v = W[(size_t)layer*40000 + k*200 + n];
        }
        wall_bf[idx] = f2bf(v);
    } else if (gidx < 1615872) {
        int idx = gidx - 1271808;
        int t = idx / 14336, r2 = idx % 14336;
        int c = r2 >> 3, jj = r2 & 7;
        int kg = c / 448, n = c % 448;
        int k = t*32 + kg*8 + jj;
        Wpt[idx] = (n < HSZ) ? f2bf(Wp[k*HSZ + n]) : (ushort)0;
    } else if (gidx < 1702400) {
        int idx = gidx - 1615872;
        int t = idx / 6656, r2 = idx % 6656;
        int c = r2 >> 3, jj = r2 & 7;
        int kg = c / 208, n = c % 208;
        int k = t*32 + kg*8 + jj;
        Wbt[idx] = (n < HID && k < HSZ) ? f2bf(Wb[n*HSZ + k]) : (ushort)0;
    }
}

// ======================= hs/ts via MFMA =======================================
__global__ __launch_bounds__(64) void k_hsts_mfma(const ushort* __restrict__ wbf,
        const ushort* __restrict__ whht, const float* __restrict__ bh,
        const float* __restrict__ bt, float* __restrict__ hs, float* __restrict__ ts) {
    int bid = blockIdx.x;
    int mt = bid / 26, nt = bid % 26;
    int lane = threadIdx.x;
    const s16x8* A = (const s16x8*)wbf;
    const s16x8* Bv = (const s16x8*)whht;
    f32x4 acc = (f32x4){0.f,0.f,0.f,0.f};
    int l15 = lane & 15, kg = lane >> 4;
    #pragma unroll 4
    for (int t = 0; t < 24; t++) {
        s16x8 a = A[(t*4 + kg)*512 + mt*16 + l15];
        s16x8 b = Bv[(t*4 + kg)*416 + nt*16 + l15];
        acc = __builtin_amdgcn_mfma_f32_16x16x32_bf16(a, b, acc, 0, 0, 0);
    }
    int col = nt*16 + l15;
    float bias; float* out; int ocol;
    if (col < 200) { bias = bh[col]; out = hs; ocol = col; }
    else if (col >= 208 && col < 408) { bias = bt[col-208]; out = ts; ocol = col-208; }
    else return;
    #pragma unroll
    for (int i = 0; i < 4; i++) {
        int r = mt*16 + (lane>>4)*4 + i;
        out[(size_t)r*200 + ocol] = gelu_tanh(acc[i] + bias);
    }
}

// ======================= biaf step1 ===========================================
__global__ void k_biaf1(const float* __restrict__ hs, const float* __restrict__ U,
                        float* __restrict__ tmp) {
    int bid = blockIdx.x;
    int b = bid >> 5, lc = (bid >> 2) & 7, h = bid & 3;
    __shared__ float hsl[16][50];
    int tid = threadIdx.x;
    for (int idx = tid; idx < 16*50; idx += 256) {
        int l = idx / 50, x = idx % 50;
        hsl[l][x] = hs[(size_t)(b*NNN + lc*16 + l)*200 + h*DHB + x];
    }
    __syncthreads();
    const float* Uh = U + (size_t)h*DHB*DHB*DHB;
    for (int o = tid; o < DHB*DHB; o += 256) {
        float a[16];
        #pragma unroll
        for (int l = 0; l < 16; l++) a[l] = 0.f;
        for (int x = 0; x < DHB; x++) {
            float u = Uh[(size_t)(o/DHB*DHB + x)*DHB + (o%DHB)];
            #pragma unroll
            for (int l = 0; l < 16; l++) a[l] += hsl[l][x]*u;
        }
        #pragma unroll
        for (int l = 0; l < 16; l++)
            tmp[((size_t)((b*NNN + lc*16 + l)*4 + h))*2500 + o] = a[l];
    }
}

// ======================= proj MFMA + LN  FUSED WITH  biaf2 ====================
// Blocks [0,1024): proj (round-14-verified wr4xwc2, 207us). Blocks [1024,1824):
// biaf2 re-strided to 512 threads. Independent work, one launch: biaf2 blocks
// backfill CUs while proj's latency-bound blocks drain. LDS = 52KB union
// (160/52=3 >= proj's VGPR-capped 2 blocks/CU -> proj occupancy unchanged).
__global__ __launch_bounds__(512, 4) void k_proj_biaf2(
        const float* __restrict__ soft, const ushort* __restrict__ Wpt,
        const float* __restrict__ hsg, const float* __restrict__ tsg,
        const float* __restrict__ ln_g, const float* __restrict__ ln_b,
        const float* __restrict__ alpha_p, ushort* __restrict__ aff_t,
        const float* __restrict__ tmp, float* __restrict__ scores)
{
    __shared__ __align__(16) char smem[52096];
    int tid = threadIdx.x;

    if (blockIdx.x >= 1024) {
        // ---------------- biaf2 path (512 threads) ----------------
        int bid = blockIdx.x - 1024;    // (b*4+h)*50+d
        int d = bid % DHB;
        int bh = bid / DHB;
        int h = bh & 3, b = bh >> 2;
        float* tmp_s = (float*)smem;                 // [128][50]  25600 B
        float* tt_s  = (float*)(smem + 25600);       // [50][132]  26400 B
        for (int idx = tid; idx < NNN*DHB; idx += 512) {
            int l = idx / DHB, y = idx % DHB;
            tmp_s[l*DHB + y] = tmp[(size_t)(((b*NNN + l)*4 + h)*DHB + d)*DHB + y];
        }
        for (int idx = tid; idx < NNN*DHB; idx += 512) {
            int k = idx / DHB, y = idx % DHB;
            tt_s[y*(NNN+4) + k] = tsg[(b*NNN + k)*200 + h*DHB + y];
        }
        __syncthreads();
        float* out = scores + (size_t)(b*HID + h*DHB + d)*NNN*NNN;
        for (int o = tid; o < NNN*32; o += 512) {
            int l = o / 32, kb = (o % 32) * 4;
            float4 acc = {0.f,0.f,0.f,0.f};
            for (int y = 0; y < DHB; y++) {
                float t = tmp_s[l*DHB + y];
                float4 v = *(const float4*)&tt_s[y*(NNN+4) + kb];
                acc.x += t*v.x; acc.y += t*v.y; acc.z += t*v.z; acc.w += t*v.w;
            }
            *(float4*)&out[l*NNN + kb] = acc;
        }
        return;
    }

    // ---------------- proj path (verified round-14 body) ----------------
    ushort* ts_s = (ushort*)smem;              // [64][200] bf16  (25600 B)
    float*  hs_s = (float*)(smem + 25600);     // [200]
    float*  g_s  = (float*)(smem + 26400);     // [402]
    float*  bb_s = (float*)(smem + 28008);     // [402]
    float*  lnred= (float*)(smem + 29616);     // [2 wc][64 r][2]

    int lane = tid & 63, w = tid >> 6;         // w 0..7
    int wr = w >> 1, wc = w & 1;               // wr 0..3 (16 rows), wc 0..1 (224 cols)
    int l15 = lane & 15, kg = lane >> 4;
    int flat0 = blockIdx.x * 64;
    int b  = flat0 >> 14;
    int m  = (flat0 >> 7) & 127;
    int nb = flat0 & 127;

    f32x4 acc[14];
    #pragma unroll
    for (int cf = 0; cf < 14; cf++) acc[cf] = (f32x4){0.f,0.f,0.f,0.f};

    const float* aBase = soft + (size_t)(flat0 + wr*16 + l15)*EMB + kg*8;
    const s16x8* Bp = (const s16x8*)Wpt;
    int bcol = wc*224 + l15;

    #pragma unroll 2
    for (int t = 0; t < 24; t++) {
        float4 f0 = *(const float4*)(aBase + t*32);
        float4 f1 = *(const float4*)(aBase + t*32 + 4);
        s16x8 af = cvt8(f0, f1);
        #pragma unroll
        for (int cf = 0; cf < 14; cf++) {
            s16x8 bfv = Bp[(size_t)t*1792 + kg*448 + bcol + cf*16];
            acc[cf] = __builtin_amdgcn_mfma_f32_16x16x32_bf16(af, bfv, acc[cf], 0, 0, 0);
        }
    }

    // ---- epilogue: add concat, LayerNorm over 402, write bf16 tiled ----
    for (int idx = tid; idx < 64*200; idx += 512) {
        int r = idx / 200, c2 = idx % 200;
        ts_s[r*200 + c2] = f2bf(tsg[((size_t)(b*NNN + nb + r))*200 + c2]);
    }
    for (int idx = tid; idx < 200; idx += 512) hs_s[idx] = hsg[((size_t)(b*NNN + m))*200 + idx];
    for (int idx = tid; idx < HSZ; idx += 512) { g_s[idx] = ln_g[idx]; bb_s[idx] = ln_b[idx]; }
    __syncthreads();

    float alpha = alpha_p[0];
    #pragma unroll
    for (int i = 0; i < 4; i++) {
        int r = wr*16 + ((lane>>4)<<2) + i;
        float s1 = 0.f, s2 = 0.f;
        #pragma unroll
        for (int cf = 0; cf < 14; cf++) {
            int j = wc*224 + cf*16 + l15;
            float v = 0.f;
            if (j < HSZ) {
                float cat;
                if (j < 200)       cat = hs_s[j];
                else if (j == 200) cat = 1.0f;
                else if (j < 401)  cat = bf2f(ts_s[r*200 + (j-201)]);
                else               cat = 1.0f;
                v = cat + alpha*acc[cf][i];
            }
            acc[cf][i] = v;
            s1 += v; s2 += v*v;
        }
        #pragma unroll
        for (int off = 1; off < 16; off <<= 1) {
            s1 += __shfl_xor(s1, off); s2 += __shfl_xor(s2, off);
        }
        if (l15 == 0) {
            lnred[(wc*64 + r)*2 + 0] = s1;
            lnred[(wc*64 + r)*2 + 1] = s2;
        }
    }
    __syncthreads();
    #pragma unroll
    for (int i = 0; i < 4; i++) {
        int r = wr*16 + ((lane>>4)<<2) + i;
        float S1 = lnred[(0*64 + r)*2 + 0] + lnred[(1*64 + r)*2 + 0];
        float S2 = lnred[(0*64 + r)*2 + 1] + lnred[(1*64 + r)*2 + 1];
        float mean = S1 * (1.0f/402.0f);
        float var  = S2 * (1.0f/402.0f) - mean*mean;
        float rinv = rsqrtf(var + 1e-5f);
        int rowglob = flat0 + r;
        int rowblock = rowglob >> 7, rlocal = rowglob & 127;
        #pragma unroll
        for (int cf = 0; cf < 14; cf++) {
            int j = wc*224 + cf*16 + l15;
            if (j < 416) {
                float outv = 0.f;
                if (j < HSZ) outv = g_s[j]*(acc[cf][i] - mean)*rinv + bb_s[j];
                int tile = j >> 5, kg2 = (j >> 3) & 3, jj = j & 7;
                aff_t[(((size_t)rowblock*13 + tile)*512 + kg2*128 + rlocal)*8 + jj] = f2bf(outv);
            }
        }
    }
}

// ======================= W_big MFMA (barrier-free, LDS-free) ==================
__global__ __launch_bounds__(256) void k_wbig_mfma(const ushort* __restrict__ aff_t,
        const ushort* __restrict__ Wbt, float* __restrict__ scores)
{
    int tid = threadIdx.x, lane = tid & 63, w = tid >> 6;
    int l15 = lane & 15, kg = lane >> 4;
    int flat0 = blockIdx.x * 128;
    int b = flat0 >> 14, local0 = flat0 & 16383;
    int rowblock = blockIdx.x;

    f32x4 acc[2][13];
    #pragma unroll
    for (int rf = 0; rf < 2; rf++)
        #pragma unroll
        for (int cf = 0; cf < 13; cf++) acc[rf][cf] = (f32x4){0.f,0.f,0.f,0.f};

    #pragma unroll 2
    for (int t = 0; t < 13; t++) {
        const s16x8* at = (const s16x8*)(aff_t + ((size_t)rowblock*13 + t)*4096);
        s16x8 af[2];
        #pragma unroll
        for (int rf = 0; rf < 2; rf++)
            af[rf] = at[kg*128 + w*32 + rf*16 + l15];
        const s16x8* btp = (const s16x8*)(Wbt + (size_t)t*6656);
        #pragma unroll
        for (int cf = 0; cf < 13; cf++) {
            s16x8 bfv = btp[kg*208 + cf*16 + l15];
            #pragma unroll
            for (int rf = 0; rf < 2; rf++)
                acc[rf][cf] = __builtin_amdgcn_mfma_f32_16x16x32_bf16(af[rf], bfv, acc[rf][cf], 0, 0, 0);
        }
    }
    #pragma unroll
    for (int cf = 0; cf < 13; cf++) {
        int ch = cf*16 + l15;
        if (ch < HID) {
            #pragma unroll
            for (int rf = 0; rf < 2; rf++) {
                size_t base = ((size_t)(b*HID + ch))*16384 + local0 + w*32 + rf*16 + ((lane>>4)<<2);
                float4 old = *(float4*)(scores + base);
                old.x += acc[rf][cf][0]; old.y += acc[rf][cf][1];
                old.z += acc[rf][cf][2]; old.w += acc[rf][cf][3];
                *(float4*)(scores + base) = old;
            }
        }
    }
}

// ======================= gather + qkv(layer0) fused ===========================
__global__ __launch_bounds__(768) void k_gather_qkv(const float* __restrict__ scores,
        const int* __restrict__ id2lr, float* __restrict__ feat,
        const ushort* __restrict__ Wlayer, const float* __restrict__ bq,
        const float* __restrict__ bk, const float* __restrict__ bv,
        float* __restrict__ q, ushort* __restrict__ kf16, ushort* __restrict__ vf16)
{
    __shared__ float tile[64][204];
    int tid = threadIdx.x;
    {
        int sl = tid & 63, cq = tid >> 6;        // cq 0..11
        int gs = blockIdx.x*64 + sl;
        int b = gs / SS;
        int l = id2lr[gs*2 + 0];
        int r = id2lr[gs*2 + 1];
        size_t base = (size_t)b*HID*16384 + l*128 + r;
        for (int c = cq; c < 200; c += 12)
            tile[sl][c] = scores[base + (size_t)c*16384];
    }
    __syncthreads();
    size_t fbase = (size_t)blockIdx.x*64*200;
    for (int idx = tid; idx < 64*200; idx += 768)
        feat[fbase + idx] = tile[idx/200][idx%200];

    int lane = tid & 63, w = tid >> 6;           // w 0..11
    int which = w >> 2, rq = w & 3;
    int l15 = lane & 15, kg = lane >> 4;
    const ushort* Bt = Wlayer + (size_t)which*46592;
    const float* bias = which == 0 ? bq : (which == 1 ? bk : bv);
    f32x4 acc[13];
    #pragma unroll
    for (int cf = 0; cf < 13; cf++) acc[cf] = (f32x4){0.f,0.f,0.f,0.f};
    int arow = rq*16 + l15;
    #pragma unroll
    for (int t = 0; t < 7; t++) {
        int k0 = t*32 + kg*8;
        s16x8 af = (s16x8){0,0,0,0,0,0,0,0};
        if (k0 + 8 <= 200) {
            float4 f0 = *(const float4*)&tile[arow][k0];
            float4 f1 = *(const float4*)&tile[arow][k0 + 4];
            af = cvt8(f0, f1);
        }
        const s16x8* btp = (const s16x8*)(Bt + (size_t)t*6656);
        #pragma unroll
        for (int cf = 0; cf < 13; cf++)
            acc[cf] = __builtin_amdgcn_mfma_f32_16x16x32_bf16(af, btp[kg*208 + cf*16 + l15], acc[cf], 0, 0, 0);
    }
    if (which == 0) {
        #pragma unroll
        for (int cf = 0; cf < 13; cf++) {
            int col = cf*16 + l15;
            if (col < 200) {
                float bi = bias[col];
                #pragma unroll
                for (int i = 0; i < 4; i++) {
                    int row = blockIdx.x*64 + rq*16 + ((lane>>4)<<2) + i;
                    q[(size_t)row*200 + col] = acc[cf][i] + bi;
                }
            }
        }
    } else {
        ushort* out16 = (which == 1) ? kf16 : vf16;
        #pragma unroll
        for (int cf = 0; cf < 13; cf++) {
            int col = cf*16 + l15;
            if (col < 200) {
                float bi = bias[col];
                #pragma unroll
                for (int i = 0; i < 4; i++) {
                    int row = blockIdx.x*64 + rq*16 + ((lane>>4)<<2) + i;
                    out16[(size_t)row*200 + col] = f2bf(acc[cf][i] + bi);
                }
            }
        }
    }
}

// ======================= qkv MFMA (layers 1,2; 2 waves/block) =================
__global__ __launch_bounds__(128) void k_qkv_mfma(const float* __restrict__ feat,
        const ushort* __restrict__ Wlayer, const float* __restrict__ bq,
        const float* __restrict__ bk, const float* __restrict__ bv,
        float* __restrict__ q, ushort* __restrict__ kf16, ushort* __restrict__ vf16)
{
    int bid = blockIdx.x;
    int which = bid % 3, mb = bid / 3;
    const ushort* Bt = Wlayer + (size_t)which*46592;
    const float* bias = which == 0 ? bq : (which == 1 ? bk : bv);
    int tid = threadIdx.x, lane = tid & 63, w = tid >> 6;   // w 0..1
    int l15 = lane & 15, kg = lane >> 4;
    int row0 = mb*32;
    const float* aRow = feat + (size_t)(row0 + w*16 + l15)*200;
    f32x4 acc[13];
    #pragma unroll
    for (int cf = 0; cf < 13; cf++) acc[cf] = (f32x4){0.f,0.f,0.f,0.f};
    #pragma unroll
    for (int t = 0; t < 7; t++) {
        int k0 = t*32 + kg*8;
        s16x8 af = (s16x8){0,0,0,0,0,0,0,0};
        if (k0 + 8 <= 200) {
            float4 f0 = *(const float4*)(aRow + k0);
            float4 f1 = *(const float4*)(aRow + k0 + 4);
            af = cvt8(f0, f1);
        }
        const s16x8* btp = (const s16x8*)(Bt + (size_t)t*6656);
        #pragma unroll
        for (int cf = 0; cf < 13; cf++)
            acc[cf] = __builtin_amdgcn_mfma_f32_16x16x32_bf16(af, btp[kg*208 + cf*16 + l15], acc[cf], 0, 0, 0);
    }
    if (which == 0) {
        #pragma unroll
        for (int cf = 0; cf < 13; cf++) {
            int col = cf*16 + l15;
            if (col < 200) {
                float bi = bias[col];
                #pragma unroll
                for (int i = 0; i < 4; i++) {
                    int row = row0 + w*16 + ((lane>>4)<<2) + i;
                    q[(size_t)row*200 + col] = acc[cf][i] + bi;
                }
            }
        }
    } else {
        ushort* out16 = (which == 1) ? kf16 : vf16;
        #pragma unroll
        for (int cf = 0; cf < 13; cf++) {
            int col = cf*16 + l15;
            if (col < 200) {
                float bi = bias[col];
                #pragma unroll
                for (int i = 0; i < 4; i++) {
                    int row = row0 + w*16 + ((lane>>4)<<2) + i;
                    out16[(size_t)row*200 + col] = f2bf(acc[cf][i] + bi);
                }
            }
        }
    }
}

// ======================= attention core (1 span / 1-wave block, bf16 K/V) =====
__global__ __launch_bounds__(64) void k_attn(const float* __restrict__ q,
        const ushort* __restrict__ kf16, const ushort* __restrict__ vf16,
        const int* __restrict__ N_idx, const float* __restrict__ head_gate,
        float* __restrict__ opre) {
    int rowg = blockIdx.x;          // b*3600+s
    int b = rowg / SS, s = rowg % SS;
    __shared__ float Kb[KKK][200];
    __shared__ float qs[200];
    __shared__ float lgs[40];
    __shared__ float at[4][KKK];
    __shared__ int idxs[KKK];
    int lane = threadIdx.x;
    if (lane < KKK) idxs[lane] = N_idx[rowg*KKK + lane];
    if (lane < 50) ((float4*)qs)[lane] = ((const float4*)(q + (size_t)rowg*200))[lane];
    __syncthreads();
    for (int i = lane; i < KKK*50; i += 64) {
        int k = i / 50, c = i % 50;
        int nb = idxs[k];
        ushort4 uv = *(const ushort4*)&kf16[((size_t)(b*SS) + nb)*200 + c*4];
        Kb[k][c*4+0] = bf2f(uv.x); Kb[k][c*4+1] = bf2f(uv.y);
        Kb[k][c*4+2] = bf2f(uv.z); Kb[k][c*4+3] = bf2f(uv.w);
    }
    __syncthreads();
    if (lane < 40) {
        int h = lane / KKK, k = lane % KKK;
        float acc = 0.f;
        #pragma unroll 10
        for (int d = 0; d < DHB; d++) acc += qs[h*DHB + d]*Kb[k][h*DHB + d];
        lgs[lane] = acc*0.141421356237309515f
                  + logf(head_gate[((size_t)(b*4 + h)*SS + s)*KKK + k] + 1e-9f);
    }
    __syncthreads();
    if (lane < 4) {
        int h = lane;
        float mx = -1e30f;
        for (int k = 0; k < KKK; k++) mx = fmaxf(mx, lgs[h*KKK + k]);
        float sum = 0.f;
        float e[KKK];
        for (int k = 0; k < KKK; k++) { e[k] = expf(lgs[h*KKK + k] - mx); sum += e[k]; }
        float inv = 1.f/sum;
        for (int k = 0; k < KKK; k++) at[h][k] = e[k]*inv;
    }
    __syncthreads();
    if (lane < 50) {
        int c0 = lane*4;
        int ha = c0/DHB, hb = (c0+1)/DHB, hc = (c0+2)/DHB, hd = (c0+3)/DHB;
        float o0=0.f, o1=0.f, o2=0.f, o3=0.f;
        #pragma unroll
        for (int k = 0; k < KKK; k++) {
            ushort4 uv = *(const ushort4*)&vf16[((size_t)(b*SS) + idxs[k])*200 + c0];
            o0 += at[ha][k]*bf2f(uv.x); o1 += at[hb][k]*bf2f(uv.y);
            o2 += at[hc][k]*bf2f(uv.z); o3 += at[hd][k]*bf2f(uv.w);
        }
        *(float4*)&opre[(size_t)rowg*200 + c0] = (float4){o0,o1,o2,o3};
    }
}

// ======================= o@Wo + residual + LN (2 waves/block, 32 rows) ========
__global__ __launch_bounds__(128) void k_oln_mfma(const float* __restrict__ opre,
        const ushort* __restrict__ Wot, const float* __restrict__ bo,
        const float* __restrict__ lngp, const float* __restrict__ lnbp,
        float* __restrict__ feat)
{
    int tid = threadIdx.x, lane = tid & 63, w = tid >> 6;   // w 0..1
    int l15 = lane & 15, kg = lane >> 4;
    int row0 = blockIdx.x*32;
    const float* aRow = opre + (size_t)(row0 + w*16 + l15)*200;
    f32x4 acc[13];
    #pragma unroll
    for (int cf = 0; cf < 13; cf++) acc[cf] = (f32x4){0.f,0.f,0.f,0.f};
    #pragma unroll
    for (int t = 0; t < 7; t++) {
        int k0 = t*32 + kg*8;
        s16x8 af = (s16x8){0,0,0,0,0,0,0,0};
        if (k0 + 8 <= 200) {
            float4 f0 = *(const float4*)(aRow + k0);
            float4 f1 = *(const float4*)(aRow + k0 + 4);
            af = cvt8(f0, f1);
        }
        const s16x8* btp = (const s16x8*)(Wot + (size_t)t*6656);
        #pragma unroll
        for (int cf = 0; cf < 13; cf++)
            acc[cf] = __builtin_amdgcn_mfma_f32_16x16x32_bf16(af, btp[kg*208 + cf*16 + l15], acc[cf], 0, 0, 0);
    }
    #pragma unroll
    for (int i = 0; i < 4; i++) {
        int row = row0 + w*16 + ((lane>>4)<<2) + i;
        float xv[13];
        float s1 = 0.f, s2 = 0.f;
        #pragma unroll
        for (int cf = 0; cf < 13; cf++) {
            int col = cf*16 + l15;
            float x = 0.f;
            if (col < 200) x = feat[(size_t)row*200 + col] + acc[cf][i] + bo[col];
            xv[cf] = x; s1 += x; s2 += x*x;
        }
        #pragma unroll
        for (int off = 1; off < 16; off <<= 1) {
            s1 += __shfl_xor(s1, off); s2 += __shfl_xor(s2, off);
        }
        float mean = s1*(1.0f/200.0f);
        float var  = s2*(1.0f/200.0f) - mean*mean;
        float rinv = rsqrtf(var + 1e-5f);
        #pragma unroll
        for (int cf = 0; cf < 13; cf++) {
            int col = cf*16 + l15;
            if (col < 200)
                feat[(size_t)row*200 + col] = lngp[col]*(xv[cf] - mean)*rinv + lnbp[col];
        }
    }
}

// ======================= scatter (span-major, LDS transpose) ==================
__global__ void k_scatter(const float* __restrict__ feat, const int* __restrict__ id2lr,
                          float* __restrict__ scores) {
    __shared__ float tile[64][201];
    int tid = threadIdx.x;
    size_t fbase = (size_t)blockIdx.x*64*200;
    for (int idx = tid; idx < 64*200; idx += 256)
        tile[idx/200][idx%200] = feat[fbase + idx];
    __syncthreads();
    int sl = tid & 63, cq = tid >> 6;
    int gs = blockIdx.x*64 + sl;
    int b = gs / SS;
    int l = id2lr[gs*2 + 0];
    int r = id2lr[gs*2 + 1];
    size_t base = (size_t)b*HID*16384 + l*128 + r;
    for (int c = cq; c < 200; c += 4)
        scores[base + (size_t)c*16384] = tile[sl][c];
}

// ======================= down-projection ======================================
__global__ void k_down(const float* __restrict__ scores, const float* __restrict__ Wd,
                       const float* __restrict__ bd, float* __restrict__ out) {
    __shared__ float wd[200][9];
    __shared__ float bds[9];
    int tid = threadIdx.x;
    for (int idx = tid; idx < 1800; idx += 128) wd[idx/9][idx%9] = Wd[idx];
    if (tid < 9) bds[tid] = bd[tid];
    __syncthreads();
    int bm = blockIdx.x;
    int b = bm / NNN, m = bm % NNN;
    int n = tid;
    float acc[9];
    #pragma unroll
    for (int k = 0; k < 9; k++) acc[k] = bds[k];
    for (int c = 0; c < 200; c++) {
        float sv = scores[((size_t)(b*HID + c)*NNN + m)*NNN + n];
        #pragma unroll
        for (int k = 0; k < 9; k++) acc[k] += sv*wd[c][k];
    }
    #pragma unroll
    for (int k = 0; k < 9; k++) out[((size_t)bm*NNN + n)*9 + k] = acc[k];
}

extern "C" void kernel_launch(void* const* d_in, const int* in_sizes, int n_in,
                              void* d_out, int out_size, void* d_ws, size_t ws_size,
                              hipStream_t stream) {
    (void)in_sizes; (void)n_in; (void)out_size; (void)ws_size;
    const float* word  = (const float*)d_in[0];
    const float* soft  = (const float*)d_in[1];
    const float* hgate = (const float*)d_in[2];
    const int*   N_idx = (const int*)d_in[3];
    const int*   id2lr = (const int*)d_in[5];
    const float* Wh = (const float*)d_in[7];  const float* bh = (const float*)d_in[8];
    const float* Wt = (const float*)d_in[9];  const float* bt = (const float*)d_in[10];
    const float* U  = (const float*)d_in[11];
    const float* Wbig = (const float*)d_in[12];
    const float* Wp = (const float*)d_in[13];
    const float* lng_a = (const float*)d_in[14]; const float* lnb_a = (const float*)d_in[15];
    const float* alpha = (const float*)d_in[16];
    const float* Wq = (const float*)d_in[17]; const float* bq = (const float*)d_in[18];
    const float* Wk = (const float*)d_in[19]; const float* bk = (const float*)d_in[20];
    const float* Wv = (const float*)d_in[21]; const float* bv = (const float*)d_in[22];
    const float* Wo = (const float*)d_in[23]; const float* bo = (const float*)d_in[24];
    const float* lng = (const float*)d_in[25]; const float* lnb = (const float*)d_in[26];
    const float* Wd = (const float*)d_in[27]; const float* bd = (const float*)d_in[28];

    float* ws = (float*)d_ws;
    float* hs     = ws;
    float* tsb    = hs + 102400;
    float* scores = tsb + 102400;
    ushort* Wpt     = (ushort*)(scores + 13107200);
    ushort* Wbt     = Wpt + 344064;
    ushort* word_bf = Wbt + 86528;
    ushort* whht_bf = word_bf + 393216;
    ushort* wall_bf = whht_bf + 319488;
    float* big    = ws + 14163200;
    float* tmp    = big;                    // dead after k_proj_biaf2
    ushort* aff_t = (ushort*)big;           // written by proj blocks...
    float* feat   = big;
    float* qb     = big + 2880000;
    ushort* kf16  = (ushort*)(big + 5760000);
    ushort* vf16  = (ushort*)(big + 8640000);
    float* opre   = big + 11520000;

    // NOTE: tmp and aff_t both alias `big`. tmp spans [0, 5.12M floats);
    // aff_t (bf16) spans [0, 13.63M floats of space). In the merged kernel,
    // biaf2 blocks READ tmp while proj blocks WRITE aff_t over the same
    // region — must be disjoint. Move aff_t past tmp: aff_t at big+5.12M
    // (27,262,976 ushorts = 13.63M floats -> ends at big+18.76M < big+28.8M
    // capacity given feat/qb/etc start fresh after proj+wbig).
    ushort* aff_t2 = (ushort*)(big + 5120000);

    k_cvt_all<<<6650, 256, 0, stream>>>(word, Wh, Wt, Wq, Wk, Wv, Wo, Wp, Wbig,
                                        word_bf, whht_bf, wall_bf, Wpt, Wbt);

    k_hsts_mfma<<<832, 64, 0, stream>>>(word_bf, whht_bf, bh, bt, hs, tsb);
    k_biaf1<<<128, 256, 0, stream>>>(hs, U, tmp);
    k_proj_biaf2<<<1824, 512, 0, stream>>>(soft, Wpt, hs, tsb, lng_a, lnb_a, alpha,
                                           aff_t2, tmp, scores);
    k_wbig_mfma<<<512, 256, 0, stream>>>(aff_t2, Wbt, scores);
    k_gather_qkv<<<225, 768, 0, stream>>>(scores, id2lr, feat, wall_bf,
                                          bq, bk, bv, qb, kf16, vf16);
    for (int i = 0; i < 3; i++) {
        k_attn<<<14400, 64, 0, stream>>>(qb, kf16, vf16, N_idx, hgate, opre);
        k_oln_mfma<<<450, 128, 0, stream>>>(opre, wall_bf + (size_t)(i*4+3)*46592,
                                            bo + i*200, lng + i*200, lnb + i*200, feat);
        if (i < 2)
            k_qkv_mfma<<<1350, 128, 0, stream>>>(feat, wall_bf + (size_t)(i+1)*4*46592,
                                                 bq + (i+1)*200, bk + (i+1)*200, bv + (i+1)*200,
                                                 qb, kf16, vf16);
    }
    k_scatter<<<225, 256, 0, stream>>>(feat, id2lr, scores);
    k_down<<<512, 128, 0, stream>>>(scores, Wd, bd, (float*)d_out);
}

// Round 19
// 651.735 us; speedup vs baseline: 1.0144x; 1.0144x over previous
//
#include <hip/hip_runtime.h>
#include <math.h>

#define BB 4
#define NNN 128
#define EMB 768
#define BIAF 200
#define HID 200
#define HHH 4
#define DHB 50
#define LLL 3
#define KKK 10
#define SS 3600
#define HSZ 402
#define CCC 200
#define NER 9

typedef short s16x8 __attribute__((ext_vector_type(8)));
typedef float f32x4 __attribute__((ext_vector_type(4)));

__device__ __forceinline__ ushort f2bf(float f) {
    union { float f; unsigned u; } c; c.f = f;
    unsigned u = c.u;
    return (ushort)((u + 0x7FFFu + ((u >> 16) & 1u)) >> 16);   // RNE
}
__device__ __forceinline__ float bf2f(ushort u) {
    union { unsigned u; float f; } c; c.u = ((unsigned)u) << 16; return c.f;
}
// 8x f32 -> bf16 fragment, pure C++ RNE (verified rounds 3-6; the
// v_cvt_pk_bf16_f32 asm variant FAILED correctness in round 7 — do not use)
__device__ __forceinline__ s16x8 cvt8(float4 f0, float4 f1) {
    s16x8 v;
    v[0]=(short)f2bf(f0.x); v[1]=(short)f2bf(f0.y); v[2]=(short)f2bf(f0.z); v[3]=(short)f2bf(f0.w);
    v[4]=(short)f2bf(f1.x); v[5]=(short)f2bf(f1.y); v[6]=(short)f2bf(f1.z); v[7]=(short)f2bf(f1.w);
    return v;
}

__device__ __forceinline__ float gelu_tanh(float x) {
    float x3 = x*x*x;
    return 0.5f*x*(1.0f + tanhf(0.79788456080286535588f*(x + 0.044715f*x3)));
}

// ======================= fused weight/input bf16 tiling =======================
__global__ void k_cvt_all(const float* __restrict__ word,
                          const float* __restrict__ Wh, const float* __restrict__ Wt,
                          const float* __restrict__ Wq, const float* __restrict__ Wk,
                          const float* __restrict__ Wv, const float* __restrict__ Wo,
                          const float* __restrict__ Wp, const float* __restrict__ Wb,
                          ushort* __restrict__ word_bf, ushort* __restrict__ whht_bf,
                          ushort* __restrict__ wall_bf, ushort* __restrict__ Wpt,
                          ushort* __restrict__ Wbt) {
    int gidx = blockIdx.x*256 + threadIdx.x;
    if (gidx < 393216) {
        int idx = gidx;
        int t = idx / 16384, r = idx % 16384;
        int c = r >> 3, j = r & 7;
        int kg = c / 512, row = c % 512;
        int k = t*32 + kg*8 + j;
        word_bf[idx] = f2bf(word[(size_t)row*EMB + k]);
    } else if (gidx < 712704) {
        int idx = gidx - 393216;
        int t = idx / 13312, r = idx % 13312;
        int c = r >> 3, j = r & 7;
        int kg = c / 416, n = c % 416;
        int k = t*32 + kg*8 + j;
        float v = 0.f;
        if (n < 200) v = Wh[k*200 + n];
        else if (n >= 208 && n < 408) v = Wt[k*200 + (n-208)];
        whht_bf[idx] = f2bf(v);
    } else if (gidx < 1271808) {
        int idx = gidx - 712704;
        int mat = idx / 46592, r = idx % 46592;
        int layer = mat >> 2, which = mat & 3;
        int t = r / 6656, r2 = r % 6656;
        int c = r2 >> 3, j = r2 & 7;
        int kg = c / 208, n = c % 208;
        int k = t*32 + kg*8 + j;
        float v = 0.f;
        if (k < 200 && n < 200) {
            const float* W = which == 0 ? Wq : (which == 1 ? Wk : (which == 2 ? Wv : Wo));
            v = W[(size_t)layer*40000 + k*200 + n];
        }
        wall_bf[idx] = f2bf(v);
    } else if (gidx < 1615872) {
        int idx = gidx - 1271808;
        int t = idx / 14336, r2 = idx % 14336;
        int c = r2 >> 3, jj = r2 & 7;
        int kg = c / 448, n = c % 448;
        int k = t*32 + kg*8 + jj;
        Wpt[idx] = (n < HSZ) ? f2bf(Wp[k*HSZ + n]) : (ushort)0;
    } else if (gidx < 1702400) {
        int idx = gidx - 1615872;
        int t = idx / 6656, r2 = idx % 6656;
        int c = r2 >> 3, jj = r2 & 7;
        int kg = c / 208, n = c % 208;
        int k = t*32 + kg*8 + jj;
        Wbt[idx] = (n < HID && k < HSZ) ? f2bf(Wb[n*HSZ + k]) : (ushort)0;
    }
}

// ======================= hs/ts via MFMA =======================================
__global__ __launch_bounds__(64) void k_hsts_mfma(const ushort* __restrict__ wbf,
        const ushort* __restrict__ whht, const float* __restrict__ bh,
        const float* __restrict__ bt, float* __restrict__ hs, float* __restrict__ ts) {
    int bid = blockIdx.x;
    int mt = bid / 26, nt = bid % 26;
    int lane = threadIdx.x;
    const s16x8* A = (const s16x8*)wbf;
    const s16x8* Bv = (const s16x8*)whht;
    f32x4 acc = (f32x4){0.f,0.f,0.f,0.f};
    int l15 = lane & 15, kg = lane >> 4;
    #pragma unroll 4
    for (int t = 0; t < 24; t++) {
        s16x8 a = A[(t*4 + kg)*512 + mt*16 + l15];
        s16x8 b = Bv[(t*4 + kg)*416 + nt*16 + l15];
        acc = __builtin_amdgcn_mfma_f32_16x16x32_bf16(a, b, acc, 0, 0, 0);
    }
    int col = nt*16 + l15;
    float bias; float* out; int ocol;
    if (col < 200) { bias = bh[col]; out = hs; ocol = col; }
    else if (col >= 208 && col < 408) { bias = bt[col-208]; out = ts; ocol = col-208; }
    else return;
    #pragma unroll
    for (int i = 0; i < 4; i++) {
        int r = mt*16 + (lane>>4)*4 + i;
        out[(size_t)r*200 + ocol] = gelu_tanh(acc[i] + bias);
    }
}

// ======================= biaf =================================================
__global__ void k_biaf1(const float* __restrict__ hs, const float* __restrict__ U,
                        float* __restrict__ tmp) {
    int bid = blockIdx.x;
    int b = bid >> 5, lc = (bid >> 2) & 7, h = bid & 3;
    __shared__ float hsl[16][50];
    int tid = threadIdx.x;
    for (int idx = tid; idx < 16*50; idx += 256) {
        int l = idx / 50, x = idx % 50;
        hsl[l][x] = hs[(size_t)(b*NNN + lc*16 + l)*200 + h*DHB + x];
    }
    __syncthreads();
    const float* Uh = U + (size_t)h*DHB*DHB*DHB;
    for (int o = tid; o < DHB*DHB; o += 256) {
        float a[16];
        #pragma unroll
        for (int l = 0; l < 16; l++) a[l] = 0.f;
        for (int x = 0; x < DHB; x++) {
            float u = Uh[(size_t)(o/DHB*DHB + x)*DHB + (o%DHB)];
            #pragma unroll
            for (int l = 0; l < 16; l++) a[l] += hsl[l][x]*u;
        }
        #pragma unroll
        for (int l = 0; l < 16; l++)
            tmp[((size_t)((b*NNN + lc*16 + l)*4 + h))*2500 + o] = a[l];
    }
}

__global__ void k_biaf2(const float* __restrict__ tmp, const float* __restrict__ ts,
                        float* __restrict__ scores) {
    int bid = blockIdx.x;           // (b*4+h)*50+d
    int d = bid % DHB;
    int bh = bid / DHB;
    int h = bh & 3, b = bh >> 2;
    __shared__ __align__(16) float tmp_s[NNN][DHB];
    __shared__ __align__(16) float tt_s[DHB][NNN + 4];
    int tid = threadIdx.x;
    for (int idx = tid; idx < NNN*DHB; idx += 256) {
        int l = idx / DHB, y = idx % DHB;
        tmp_s[l][y] = tmp[(size_t)(((b*NNN + l)*4 + h)*DHB + d)*DHB + y];
    }
    for (int idx = tid; idx < NNN*DHB; idx += 256) {
        int k = idx / DHB, y = idx % DHB;
        tt_s[y][k] = ts[(b*NNN + k)*200 + h*DHB + y];
    }
    __syncthreads();
    float* out = scores + (size_t)(b*HID + h*DHB + d)*NNN*NNN;
    for (int o = tid; o < NNN*32; o += 256) {
        int l = o / 32, kb = (o % 32) * 4;
        float4 acc = {0.f,0.f,0.f,0.f};
        for (int y = 0; y < DHB; y++) {
            float t = tmp_s[l][y];
            float4 v = *(const float4*)&tt_s[y][kb];
            acc.x += t*v.x; acc.y += t*v.y; acc.z += t*v.z; acc.w += t*v.w;
        }
        *(float4*)&out[l*NNN + kb] = acc;
    }
}

// ======================= proj MFMA + fused LN (wr4 x wc2 split) ===============
// Verified best: 207 us. acc 14 f32x4 = 56 regs; (512,4) only — (512,8)
// spills (round 10), 16-row blocks slower (round 12), biaf2-merge slower (r18).
__global__ __launch_bounds__(512, 4) void k_proj_mfma(
        const float* __restrict__ soft, const ushort* __restrict__ Wpt,
        const float* __restrict__ hsg, const float* __restrict__ tsg,
        const float* __restrict__ ln_g, const float* __restrict__ ln_b,
        const float* __restrict__ alpha_p, ushort* __restrict__ aff_t)
{
    __shared__ __align__(16) char smem[32768];
    ushort* ts_s = (ushort*)smem;              // [64][200] bf16  (25600 B)
    float*  hs_s = (float*)(smem + 25600);     // [200]
    float*  g_s  = (float*)(smem + 26400);     // [402]
    float*  bb_s = (float*)(smem + 28008);     // [402]
    float*  lnred= (float*)(smem + 29616);     // [2 wc][64 r][2]

    int tid = threadIdx.x;
    int lane = tid & 63, w = tid >> 6;         // w 0..7
    int wr = w >> 1, wc = w & 1;               // wr 0..3 (16 rows), wc 0..1 (224 cols)
    int l15 = lane & 15, kg = lane >> 4;
    int flat0 = blockIdx.x * 64;
    int b  = flat0 >> 14;
    int m  = (flat0 >> 7) & 127;
    int nb = flat0 & 127;

    f32x4 acc[14];
    #pragma unroll
    for (int cf = 0; cf < 14; cf++) acc[cf] = (f32x4){0.f,0.f,0.f,0.f};

    const float* aBase = soft + (size_t)(flat0 + wr*16 + l15)*EMB + kg*8;
    const s16x8* Bp = (const s16x8*)Wpt;
    int bcol = wc*224 + l15;

    #pragma unroll 2
    for (int t = 0; t < 24; t++) {
        float4 f0 = *(const float4*)(aBase + t*32);
        float4 f1 = *(const float4*)(aBase + t*32 + 4);
        s16x8 af = cvt8(f0, f1);
        #pragma unroll
        for (int cf = 0; cf < 14; cf++) {
            s16x8 bfv = Bp[(size_t)t*1792 + kg*448 + bcol + cf*16];
            acc[cf] = __builtin_amdgcn_mfma_f32_16x16x32_bf16(af, bfv, acc[cf], 0, 0, 0);
        }
    }

    // ---- epilogue: add concat, LayerNorm over 402, write bf16 tiled ----
    for (int idx = tid; idx < 64*200; idx += 512) {
        int r = idx / 200, c2 = idx % 200;
        ts_s[r*200 + c2] = f2bf(tsg[((size_t)(b*NNN + nb + r))*200 + c2]);
    }
    for (int idx = tid; idx < 200; idx += 512) hs_s[idx] = hsg[((size_t)(b*NNN + m))*200 + idx];
    for (int idx = tid; idx < HSZ; idx += 512) { g_s[idx] = ln_g[idx]; bb_s[idx] = ln_b[idx]; }
    __syncthreads();

    float alpha = alpha_p[0];
    #pragma unroll
    for (int i = 0; i < 4; i++) {
        int r = wr*16 + ((lane>>4)<<2) + i;
        float s1 = 0.f, s2 = 0.f;
        #pragma unroll
        for (int cf = 0; cf < 14; cf++) {
            int j = wc*224 + cf*16 + l15;
            float v = 0.f;
            if (j < HSZ) {
                float cat;
                if (j < 200)       cat = hs_s[j];
                else if (j == 200) cat = 1.0f;
                else if (j < 401)  cat = bf2f(ts_s[r*200 + (j-201)]);
                else               cat = 1.0f;
                v = cat + alpha*acc[cf][i];
            }
            acc[cf][i] = v;
            s1 += v; s2 += v*v;
        }
        #pragma unroll
        for (int off = 1; off < 16; off <<= 1) {
            s1 += __shfl_xor(s1, off); s2 += __shfl_xor(s2, off);
        }
        if (l15 == 0) {
            lnred[(wc*64 + r)*2 + 0] = s1;
            lnred[(wc*64 + r)*2 + 1] = s2;
        }
    }
    __syncthreads();
    #pragma unroll
    for (int i = 0; i < 4; i++) {
        int r = wr*16 + ((lane>>4)<<2) + i;
        float S1 = lnred[(0*64 + r)*2 + 0] + lnred[(1*64 + r)*2 + 0];
        float S2 = lnred[(0*64 + r)*2 + 1] + lnred[(1*64 + r)*2 + 1];
        float mean = S1 * (1.0f/402.0f);
        float var  = S2 * (1.0f/402.0f) - mean*mean;
        float rinv = rsqrtf(var + 1e-5f);
        int rowglob = flat0 + r;
        int rowblock = rowglob >> 7, rlocal = rowglob & 127;
        #pragma unroll
        for (int cf = 0; cf < 14; cf++) {
            int j = wc*224 + cf*16 + l15;
            if (j < 416) {
                float outv = 0.f;
                if (j < HSZ) outv = g_s[j]*(acc[cf][i] - mean)*rinv + bb_s[j];
                int tile = j >> 5, kg2 = (j >> 3) & 3, jj = j & 7;
                aff_t[(((size_t)rowblock*13 + tile)*512 + kg2*128 + rlocal)*8 + jj] = f2bf(outv);
            }
        }
    }
}

// ======================= W_big MFMA (barrier-free, LDS-free) ==================
__global__ __launch_bounds__(256) void k_wbig_mfma(const ushort* __restrict__ aff_t,
        const ushort* __restrict__ Wbt, float* __restrict__ scores)
{
    int tid = threadIdx.x, lane = tid & 63, w = tid >> 6;
    int l15 = lane & 15, kg = lane >> 4;
    int flat0 = blockIdx.x * 128;
    int b = flat0 >> 14, local0 = flat0 & 16383;
    int rowblock = blockIdx.x;

    f32x4 acc[2][13];
    #pragma unroll
    for (int rf = 0; rf < 2; rf++)
        #pragma unroll
        for (int cf = 0; cf < 13; cf++) acc[rf][cf] = (f32x4){0.f,0.f,0.f,0.f};

    #pragma unroll 2
    for (int t = 0; t < 13; t++) {
        const s16x8* at = (const s16x8*)(aff_t + ((size_t)rowblock*13 + t)*4096);
        s16x8 af[2];
        #pragma unroll
        for (int rf = 0; rf < 2; rf++)
            af[rf] = at[kg*128 + w*32 + rf*16 + l15];
        const s16x8* btp = (const s16x8*)(Wbt + (size_t)t*6656);
        #pragma unroll
        for (int cf = 0; cf < 13; cf++) {
            s16x8 bfv = btp[kg*208 + cf*16 + l15];
            #pragma unroll
            for (int rf = 0; rf < 2; rf++)
                acc[rf][cf] = __builtin_amdgcn_mfma_f32_16x16x32_bf16(af[rf], bfv, acc[rf][cf], 0, 0, 0);
        }
    }
    #pragma unroll
    for (int cf = 0; cf < 13; cf++) {
        int ch = cf*16 + l15;
        if (ch < HID) {
            #pragma unroll
            for (int rf = 0; rf < 2; rf++) {
                size_t base = ((size_t)(b*HID + ch))*16384 + local0 + w*32 + rf*16 + ((lane>>4)<<2);
                float4 old = *(float4*)(scores + base);
                old.x += acc[rf][cf][0]; old.y += acc[rf][cf][1];
                old.z += acc[rf][cf][2]; old.w += acc[rf][cf][3];
                *(float4*)(scores + base) = old;
            }
        }
    }
}

// ======================= gather + qkv(layer0) fused ===========================
__global__ __launch_bounds__(768) void k_gather_qkv(const float* __restrict__ scores,
        const int* __restrict__ id2lr, float* __restrict__ feat,
        const ushort* __restrict__ Wlayer, const float* __restrict__ bq,
        const float* __restrict__ bk, const float* __restrict__ bv,
        float* __restrict__ q, ushort* __restrict__ kf16, ushort* __restrict__ vf16)
{
    __shared__ float tile[64][204];
    int tid = threadIdx.x;
    {
        int sl = tid & 63, cq = tid >> 6;        // cq 0..11
        int gs = blockIdx.x*64 + sl;
        int b = gs / SS;
        int l = id2lr[gs*2 + 0];
        int r = id2lr[gs*2 + 1];
        size_t base = (size_t)b*HID*16384 + l*128 + r;
        for (int c = cq; c < 200; c += 12)
            tile[sl][c] = scores[base + (size_t)c*16384];
    }
    __syncthreads();
    size_t fbase = (size_t)blockIdx.x*64*200;
    for (int idx = tid; idx < 64*200; idx += 768)
        feat[fbase + idx] = tile[idx/200][idx%200];

    int lane = tid & 63, w = tid >> 6;           // w 0..11
    int which = w >> 2, rq = w & 3;
    int l15 = lane & 15, kg = lane >> 4;
    const ushort* Bt = Wlayer + (size_t)which*46592;
    const float* bias = which == 0 ? bq : (which == 1 ? bk : bv);
    f32x4 acc[13];
    #pragma unroll
    for (int cf = 0; cf < 13; cf++) acc[cf] = (f32x4){0.f,0.f,0.f,0.f};
    int arow = rq*16 + l15;
    #pragma unroll
    for (int t = 0; t < 7; t++) {
        int k0 = t*32 + kg*8;
        s16x8 af = (s16x8){0,0,0,0,0,0,0,0};
        if (k0 + 8 <= 200) {
            float4 f0 = *(const float4*)&tile[arow][k0];
            float4 f1 = *(const float4*)&tile[arow][k0 + 4];
            af = cvt8(f0, f1);
        }
        const s16x8* btp = (const s16x8*)(Bt + (size_t)t*6656);
        #pragma unroll
        for (int cf = 0; cf < 13; cf++)
            acc[cf] = __builtin_amdgcn_mfma_f32_16x16x32_bf16(af, btp[kg*208 + cf*16 + l15], acc[cf], 0, 0, 0);
    }
    if (which == 0) {
        #pragma unroll
        for (int cf = 0; cf < 13; cf++) {
            int col = cf*16 + l15;
            if (col < 200) {
                float bi = bias[col];
                #pragma unroll
                for (int i = 0; i < 4; i++) {
                    int row = blockIdx.x*64 + rq*16 + ((lane>>4)<<2) + i;
                    q[(size_t)row*200 + col] = acc[cf][i] + bi;
                }
            }
        }
    } else {
        ushort* out16 = (which == 1) ? kf16 : vf16;
        #pragma unroll
        for (int cf = 0; cf < 13; cf++) {
            int col = cf*16 + l15;
            if (col < 200) {
                float bi = bias[col];
                #pragma unroll
                for (int i = 0; i < 4; i++) {
                    int row = blockIdx.x*64 + rq*16 + ((lane>>4)<<2) + i;
                    out16[(size_t)row*200 + col] = f2bf(acc[cf][i] + bi);
                }
            }
        }
    }
}

// ======================= qkv MFMA (layers 1,2; 2 waves/block) =================
__global__ __launch_bounds__(128) void k_qkv_mfma(const float* __restrict__ feat,
        const ushort* __restrict__ Wlayer, const float* __restrict__ bq,
        const float* __restrict__ bk, const float* __restrict__ bv,
        float* __restrict__ q, ushort* __restrict__ kf16, ushort* __restrict__ vf16)
{
    int bid = blockIdx.x;
    int which = bid % 3, mb = bid / 3;
    const ushort* Bt = Wlayer + (size_t)which*46592;
    const float* bias = which == 0 ? bq : (which == 1 ? bk : bv);
    int tid = threadIdx.x, lane = tid & 63, w = tid >> 6;   // w 0..1
    int l15 = lane & 15, kg = lane >> 4;
    int row0 = mb*32;
    const float* aRow = feat + (size_t)(row0 + w*16 + l15)*200;
    f32x4 acc[13];
    #pragma unroll
    for (int cf = 0; cf < 13; cf++) acc[cf] = (f32x4){0.f,0.f,0.f,0.f};
    #pragma unroll
    for (int t = 0; t < 7; t++) {
        int k0 = t*32 + kg*8;
        s16x8 af = (s16x8){0,0,0,0,0,0,0,0};
        if (k0 + 8 <= 200) {
            float4 f0 = *(const float4*)(aRow + k0);
            float4 f1 = *(const float4*)(aRow + k0 + 4);
            af = cvt8(f0, f1);
        }
        const s16x8* btp = (const s16x8*)(Bt + (size_t)t*6656);
        #pragma unroll
        for (int cf = 0; cf < 13; cf++)
            acc[cf] = __builtin_amdgcn_mfma_f32_16x16x32_bf16(af, btp[kg*208 + cf*16 + l15], acc[cf], 0, 0, 0);
    }
    if (which == 0) {
        #pragma unroll
        for (int cf = 0; cf < 13; cf++) {
            int col = cf*16 + l15;
            if (col < 200) {
                float bi = bias[col];
                #pragma unroll
                for (int i = 0; i < 4; i++) {
                    int row = row0 + w*16 + ((lane>>4)<<2) + i;
                    q[(size_t)row*200 + col] = acc[cf][i] + bi;
                }
            }
        }
    } else {
        ushort* out16 = (which == 1) ? kf16 : vf16;
        #pragma unroll
        for (int cf = 0; cf < 13; cf++) {
            int col = cf*16 + l15;
            if (col < 200) {
                float bi = bias[col];
                #pragma unroll
                for (int i = 0; i < 4; i++) {
                    int row = row0 + w*16 + ((lane>>4)<<2) + i;
                    out16[(size_t)row*200 + col] = f2bf(acc[cf][i] + bi);
                }
            }
        }
    }
}

// ======================= attention core (1 span / 1-wave block, bf16 K/V) =====
__global__ __launch_bounds__(64) void k_attn(const float* __restrict__ q,
        const ushort* __restrict__ kf16, const ushort* __restrict__ vf16,
        const int* __restrict__ N_idx, const float* __restrict__ head_gate,
        float* __restrict__ opre) {
    int rowg = blockIdx.x;          // b*3600+s
    int b = rowg / SS, s = rowg % SS;
    __shared__ float Kb[KKK][200];
    __shared__ float qs[200];
    __shared__ float lgs[40];
    __shared__ float at[4][KKK];
    __shared__ int idxs[KKK];
    int lane = threadIdx.x;
    if (lane < KKK) idxs[lane] = N_idx[rowg*KKK + lane];
    if (lane < 50) ((float4*)qs)[lane] = ((const float4*)(q + (size_t)rowg*200))[lane];
    __syncthreads();
    for (int i = lane; i < KKK*50; i += 64) {
        int k = i / 50, c = i % 50;
        int nb = idxs[k];
        ushort4 uv = *(const ushort4*)&kf16[((size_t)(b*SS) + nb)*200 + c*4];
        Kb[k][c*4+0] = bf2f(uv.x); Kb[k][c*4+1] = bf2f(uv.y);
        Kb[k][c*4+2] = bf2f(uv.z); Kb[k][c*4+3] = bf2f(uv.w);
    }
    __syncthreads();
    if (lane < 40) {
        int h = lane / KKK, k = lane % KKK;
        float acc = 0.f;
        #pragma unroll 10
        for (int d = 0; d < DHB; d++) acc += qs[h*DHB + d]*Kb[k][h*DHB + d];
        lgs[lane] = acc*0.141421356237309515f
                  + logf(head_gate[((size_t)(b*4 + h)*SS + s)*KKK + k] + 1e-9f);
    }
    __syncthreads();
    if (lane < 4) {
        int h = lane;
        float mx = -1e30f;
        for (int k = 0; k < KKK; k++) mx = fmaxf(mx, lgs[h*KKK + k]);
        float sum = 0.f;
        float e[KKK];
        for (int k = 0; k < KKK; k++) { e[k] = expf(lgs[h*KKK + k] - mx); sum += e[k]; }
        float inv = 1.f/sum;
        for (int k = 0; k < KKK; k++) at[h][k] = e[k]*inv;
    }
    __syncthreads();
    if (lane < 50) {
        int c0 = lane*4;
        int ha = c0/DHB, hb = (c0+1)/DHB, hc = (c0+2)/DHB, hd = (c0+3)/DHB;
        float o0=0.f, o1=0.f, o2=0.f, o3=0.f;
        #pragma unroll
        for (int k = 0; k < KKK; k++) {
            ushort4 uv = *(const ushort4*)&vf16[((size_t)(b*SS) + idxs[k])*200 + c0];
            o0 += at[ha][k]*bf2f(uv.x); o1 += at[hb][k]*bf2f(uv.y);
            o2 += at[hc][k]*bf2f(uv.z); o3 += at[hd][k]*bf2f(uv.w);
        }
        *(float4*)&opre[(size_t)rowg*200 + c0] = (float4){o0,o1,o2,o3};
    }
}

// ======================= o@Wo + residual + LN (2 waves/block, 32 rows) ========
__global__ __launch_bounds__(128) void k_oln_mfma(const float* __restrict__ opre,
        const ushort* __restrict__ Wot, const float* __restrict__ bo,
        const float* __restrict__ lngp, const float* __restrict__ lnbp,
        float* __restrict__ feat)
{
    int tid = threadIdx.x, lane = tid & 63, w = tid >> 6;   // w 0..1
    int l15 = lane & 15, kg = lane >> 4;
    int row0 = blockIdx.x*32;
    const float* aRow = opre + (size_t)(row0 + w*16 + l15)*200;
    f32x4 acc[13];
    #pragma unroll
    for (int cf = 0; cf < 13; cf++) acc[cf] = (f32x4){0.f,0.f,0.f,0.f};
    #pragma unroll
    for (int t = 0; t < 7; t++) {
        int k0 = t*32 + kg*8;
        s16x8 af = (s16x8){0,0,0,0,0,0,0,0};
        if (k0 + 8 <= 200) {
            float4 f0 = *(const float4*)(aRow + k0);
            float4 f1 = *(const float4*)(aRow + k0 + 4);
            af = cvt8(f0, f1);
        }
        const s16x8* btp = (const s16x8*)(Wot + (size_t)t*6656);
        #pragma unroll
        for (int cf = 0; cf < 13; cf++)
            acc[cf] = __builtin_amdgcn_mfma_f32_16x16x32_bf16(af, btp[kg*208 + cf*16 + l15], acc[cf], 0, 0, 0);
    }
    #pragma unroll
    for (int i = 0; i < 4; i++) {
        int row = row0 + w*16 + ((lane>>4)<<2) + i;
        float xv[13];
        float s1 = 0.f, s2 = 0.f;
        #pragma unroll
        for (int cf = 0; cf < 13; cf++) {
            int col = cf*16 + l15;
            float x = 0.f;
            if (col < 200) x = feat[(size_t)row*200 + col] + acc[cf][i] + bo[col];
            xv[cf] = x; s1 += x; s2 += x*x;
        }
        #pragma unroll
        for (int off = 1; off < 16; off <<= 1) {
            s1 += __shfl_xor(s1, off); s2 += __shfl_xor(s2, off);
        }
        float mean = s1*(1.0f/200.0f);
        float var  = s2*(1.0f/200.0f) - mean*mean;
        float rinv = rsqrtf(var + 1e-5f);
        #pragma unroll
        for (int cf = 0; cf < 13; cf++) {
            int col = cf*16 + l15;
            if (col < 200)
                feat[(size_t)row*200 + col] = lngp[col]*(xv[cf] - mean)*rinv + lnbp[col];
        }
    }
}

// ======================= scatter (span-major, LDS transpose) ==================
__global__ void k_scatter(const float* __restrict__ feat, const int* __restrict__ id2lr,
                          float* __restrict__ scores) {
    __shared__ float tile[64][201];
    int tid = threadIdx.x;
    size_t fbase = (size_t)blockIdx.x*64*200;
    for (int idx = tid; idx < 64*200; idx += 256)
        tile[idx/200][idx%200] = feat[fbase + idx];
    __syncthreads();
    int sl = tid & 63, cq = tid >> 6;
    int gs = blockIdx.x*64 + sl;
    int b = gs / SS;
    int l = id2lr[gs*2 + 0];
    int r = id2lr[gs*2 + 1];
    size_t base = (size_t)b*HID*16384 + l*128 + r;
    for (int c = cq; c < 200; c += 4)
        scores[base + (size_t)c*16384] = tile[sl][c];
}

// ======================= down-projection ======================================
__global__ void k_down(const float* __restrict__ scores, const float* __restrict__ Wd,
                       const float* __restrict__ bd, float* __restrict__ out) {
    __shared__ float wd[200][9];
    __shared__ float bds[9];
    int tid = threadIdx.x;
    for (int idx = tid; idx < 1800; idx += 128) wd[idx/9][idx%9] = Wd[idx];
    if (tid < 9) bds[tid] = bd[tid];
    __syncthreads();
    int bm = blockIdx.x;
    int b = bm / NNN, m = bm % NNN;
    int n = tid;
    float acc[9];
    #pragma unroll
    for (int k = 0; k < 9; k++) acc[k] = bds[k];
    for (int c = 0; c < 200; c++) {
        float sv = scores[((size_t)(b*HID + c)*NNN + m)*NNN + n];
        #pragma unroll
        for (int k = 0; k < 9; k++) acc[k] += sv*wd[c][k];
    }
    #pragma unroll
    for (int k = 0; k < 9; k++) out[((size_t)bm*NNN + n)*9 + k] = acc[k];
}

extern "C" void kernel_launch(void* const* d_in, const int* in_sizes, int n_in,
                              void* d_out, int out_size, void* d_ws, size_t ws_size,
                              hipStream_t stream) {
    (void)in_sizes; (void)n_in; (void)out_size; (void)ws_size;
    const float* word  = (const float*)d_in[0];
    const float* soft  = (const float*)d_in[1];
    const float* hgate = (const float*)d_in[2];
    const int*   N_idx = (const int*)d_in[3];
    const int*   id2lr = (const int*)d_in[5];
    const float* Wh = (const float*)d_in[7];  const float* bh = (const float*)d_in[8];
    const float* Wt = (const float*)d_in[9];  const float* bt = (const float*)d_in[10];
    const float* U  = (const float*)d_in[11];
    const float* Wbig = (const float*)d_in[12];
    const float* Wp = (const float*)d_in[13];
    const float* lng_a = (const float*)d_in[14]; const float* lnb_a = (const float*)d_in[15];
    const float* alpha = (const float*)d_in[16];
    const float* Wq = (const float*)d_in[17]; const float* bq = (const float*)d_in[18];
    const float* Wk = (const float*)d_in[19]; const float* bk = (const float*)d_in[20];
    const float* Wv = (const float*)d_in[21]; const float* bv = (const float*)d_in[22];
    const float* Wo = (const float*)d_in[23]; const float* bo = (const float*)d_in[24];
    const float* lng = (const float*)d_in[25]; const float* lnb = (const float*)d_in[26];
    const float* Wd = (const float*)d_in[27]; const float* bd = (const float*)d_in[28];

    float* ws = (float*)d_ws;
    float* hs     = ws;
    float* tsb    = hs + 102400;
    float* scores = tsb + 102400;
    ushort* Wpt     = (ushort*)(scores + 13107200);
    ushort* Wbt     = Wpt + 344064;
    ushort* word_bf = Wbt + 86528;
    ushort* whht_bf = word_bf + 393216;
    ushort* wall_bf = whht_bf + 319488;
    float* big    = ws + 14163200;
    float* tmp    = big;
    ushort* aff_t = (ushort*)big;
    float* feat   = big;
    float* qb     = big + 2880000;
    ushort* kf16  = (ushort*)(big + 5760000);
    ushort* vf16  = (ushort*)(big + 8640000);
    float* opre   = big + 11520000;

    k_cvt_all<<<6650, 256, 0, stream>>>(word, Wh, Wt, Wq, Wk, Wv, Wo, Wp, Wbig,
                                        word_bf, whht_bf, wall_bf, Wpt, Wbt);

    k_hsts_mfma<<<832, 64, 0, stream>>>(word_bf, whht_bf, bh, bt, hs, tsb);
    k_biaf1<<<128, 256, 0, stream>>>(hs, U, tmp);
    k_biaf2<<<800, 256, 0, stream>>>(tmp, tsb, scores);
    k_proj_mfma<<<1024, 512, 0, stream>>>(soft, Wpt, hs, tsb, lng_a, lnb_a, alpha, aff_t);
    k_wbig_mfma<<<512, 256, 0, stream>>>(aff_t, Wbt, scores);
    k_gather_qkv<<<225, 768, 0, stream>>>(scores, id2lr, feat, wall_bf,
                                          bq, bk, bv, qb, kf16, vf16);
    for (int i = 0; i < 3; i++) {
        k_attn<<<14400, 64, 0, stream>>>(qb, kf16, vf16, N_idx, hgate, opre);
        k_oln_mfma<<<450, 128, 0, stream>>>(opre, wall_bf + (size_t)(i*4+3)*46592,
                                            bo + i*200, lng + i*200, lnb + i*200, feat);
        if (i < 2)
            k_qkv_mfma<<<1350, 128, 0, stream>>>(feat, wall_bf + (size_t)(i+1)*4*46592,
                                                 bq + (i+1)*200, bk + (i+1)*200, bv + (i+1)*200,
                                                 qb, kf16, vf16);
    }
    k_scatter<<<225, 256, 0, stream>>>(feat, id2lr, scores);
    k_down<<<512, 128, 0, stream>>>(scores, Wd, bd, (float*)d_out);
}

// Round 20
// 614.629 us; speedup vs baseline: 1.0757x; 1.0604x over previous
//
#include <hip/hip_runtime.h>
#include <math.h>

#define BB 4
#define NNN 128
#define EMB 768
#define BIAF 200
#define HID 200
#define HHH 4
#define DHB 50
#define LLL 3
#define KKK 10
#define SS 3600
#define HSZ 402
#define CCC 200
#define NER 9

typedef short s16x8 __attribute__((ext_vector_type(8)));
typedef float f32x4 __attribute__((ext_vector_type(4)));

__device__ __forceinline__ ushort f2bf(float f) {
    union { float f; unsigned u; } c; c.f = f;
    unsigned u = c.u;
    return (ushort)((u + 0x7FFFu + ((u >> 16) & 1u)) >> 16);   // RNE
}
__device__ __forceinline__ float bf2f(ushort u) {
    union { unsigned u; float f; } c; c.u = ((unsigned)u) << 16; return c.f;
}
// 8x f32 -> bf16 fragment, pure C++ RNE (verified rounds 3-6; the
// v_cvt_pk_bf16_f32 asm variant FAILED correctness in round 7 — do not use)
__device__ __forceinline__ s16x8 cvt8(float4 f0, float4 f1) {
    s16x8 v;
    v[0]=(short)f2bf(f0.x); v[1]=(short)f2bf(f0.y); v[2]=(short)f2bf(f0.z); v[3]=(short)f2bf(f0.w);
    v[4]=(short)f2bf(f1.x); v[5]=(short)f2bf(f1.y); v[6]=(short)f2bf(f1.z); v[7]=(short)f2bf(f1.w);
    return v;
}

__device__ __forceinline__ float gelu_tanh(float x) {
    float x3 = x*x*x;
    return 0.5f*x*(1.0f + tanhf(0.79788456080286535588f*(x + 0.044715f*x3)));
}

// ======================= fused weight/input bf16 tiling =======================
__global__ void k_cvt_all(const float* __restrict__ word,
                          const float* __restrict__ Wh, const float* __restrict__ Wt,
                          const float* __restrict__ Wq, const float* __restrict__ Wk,
                          const float* __restrict__ Wv, const float* __restrict__ Wo,
                          const float* __restrict__ Wp, const float* __restrict__ Wb,
                          ushort* __restrict__ word_bf, ushort* __restrict__ whht_bf,
                          ushort* __restrict__ wall_bf, ushort* __restrict__ Wpt,
                          ushort* __restrict__ Wbt) {
    int gidx = blockIdx.x*256 + threadIdx.x;
    if (gidx < 393216) {
        int idx = gidx;
        int t = idx / 16384, r = idx % 16384;
        int c = r >> 3, j = r & 7;
        int kg = c / 512, row = c % 512;
        int k = t*32 + kg*8 + j;
        word_bf[idx] = f2bf(word[(size_t)row*EMB + k]);
    } else if (gidx < 712704) {
        int idx = gidx - 393216;
        int t = idx / 13312, r = idx % 13312;
        int c = r >> 3, j = r & 7;
        int kg = c / 416, n = c % 416;
        int k = t*32 + kg*8 + j;
        float v = 0.f;
        if (n < 200) v = Wh[k*200 + n];
        else if (n >= 208 && n < 408) v = Wt[k*200 + (n-208)];
        whht_bf[idx] = f2bf(v);
    } else if (gidx < 1271808) {
        int idx = gidx - 712704;
        int mat = idx / 46592, r = idx % 46592;
        int layer = mat >> 2, which = mat & 3;
        int t = r / 6656, r2 = r % 6656;
        int c = r2 >> 3, j = r2 & 7;
        int kg = c / 208, n = c % 208;
        int k = t*32 + kg*8 + j;
        float v = 0.f;
        if (k < 200 && n < 200) {
            const float* W = which == 0 ? Wq : (which == 1 ? Wk : (which == 2 ? Wv : Wo));
            v = W[(size_t)layer*40000 + k*200 + n];
        }
        wall_bf[idx] = f2bf(v);
    } else if (gidx < 1615872) {
        int idx = gidx - 1271808;
        int t = idx / 14336, r2 = idx % 14336;
        int c = r2 >> 3, jj = r2 & 7;
        int kg = c / 448, n = c % 448;
        int k = t*32 + kg*8 + jj;
        Wpt[idx] = (n < HSZ) ? f2bf(Wp[k*HSZ + n]) : (ushort)0;
    } else if (gidx < 1702400) {
        int idx = gidx - 1615872;
        int t = idx / 6656, r2 = idx % 6656;
        int c = r2 >> 3, jj = r2 & 7;
        int kg = c / 208, n = c % 208;
        int k = t*32 + kg*8 + jj;
        Wbt[idx] = (n < HID && k < HSZ) ? f2bf(Wb[n*HSZ + k]) : (ushort)0;
    }
}

// ======================= hs/ts via MFMA =======================================
__global__ __launch_bounds__(64) void k_hsts_mfma(const ushort* __restrict__ wbf,
        const ushort* __restrict__ whht, const float* __restrict__ bh,
        const float* __restrict__ bt, float* __restrict__ hs, float* __restrict__ ts) {
    int bid = blockIdx.x;
    int mt = bid / 26, nt = bid % 26;
    int lane = threadIdx.x;
    const s16x8* A = (const s16x8*)wbf;
    const s16x8* Bv = (const s16x8*)whht;
    f32x4 acc = (f32x4){0.f,0.f,0.f,0.f};
    int l15 = lane & 15, kg = lane >> 4;
    #pragma unroll 4
    for (int t = 0; t < 24; t++) {
        s16x8 a = A[(t*4 + kg)*512 + mt*16 + l15];
        s16x8 b = Bv[(t*4 + kg)*416 + nt*16 + l15];
        acc = __builtin_amdgcn_mfma_f32_16x16x32_bf16(a, b, acc, 0, 0, 0);
    }
    int col = nt*16 + l15;
    float bias; float* out; int ocol;
    if (col < 200) { bias = bh[col]; out = hs; ocol = col; }
    else if (col >= 208 && col < 408) { bias = bt[col-208]; out = ts; ocol = col-208; }
    else return;
    #pragma unroll
    for (int i = 0; i < 4; i++) {
        int r = mt*16 + (lane>>4)*4 + i;
        out[(size_t)r*200 + ocol] = gelu_tanh(acc[i] + bias);
    }
}

// ======================= biaf step1 (o-range split, 256 blocks) ===============
__global__ void k_biaf1(const float* __restrict__ hs, const float* __restrict__ U,
                        float* __restrict__ tmp) {
    int bid = blockIdx.x;
    int oh = bid & 1;
    int rest = bid >> 1;
    int b = rest >> 5, lc = (rest >> 2) & 7, h = rest & 3;
    __shared__ float hsl[16][50];
    int tid = threadIdx.x;
    for (int idx = tid; idx < 16*50; idx += 256) {
        int l = idx / 50, x = idx % 50;
        hsl[l][x] = hs[(size_t)(b*NNN + lc*16 + l)*200 + h*DHB + x];
    }
    __syncthreads();
    const float* Uh = U + (size_t)h*DHB*DHB*DHB;
    for (int o = oh*1250 + tid; o < oh*1250 + 1250; o += 256) {
        float a[16];
        #pragma unroll
        for (int l = 0; l < 16; l++) a[l] = 0.f;
        for (int x = 0; x < DHB; x++) {
            float u = Uh[(size_t)(o/DHB*DHB + x)*DHB + (o%DHB)];
            #pragma unroll
            for (int l = 0; l < 16; l++) a[l] += hsl[l][x]*u;
        }
        #pragma unroll
        for (int l = 0; l < 16; l++)
            tmp[((size_t)((b*NNN + lc*16 + l)*4 + h))*2500 + o] = a[l];
    }
}

__global__ void k_biaf2(const float* __restrict__ tmp, const float* __restrict__ ts,
                        float* __restrict__ scores) {
    int bid = blockIdx.x;           // (b*4+h)*50+d
    int d = bid % DHB;
    int bh = bid / DHB;
    int h = bh & 3, b = bh >> 2;
    __shared__ __align__(16) float tmp_s[NNN][DHB];
    __shared__ __align__(16) float tt_s[DHB][NNN + 4];
    int tid = threadIdx.x;
    for (int idx = tid; idx < NNN*DHB; idx += 256) {
        int l = idx / DHB, y = idx % DHB;
        tmp_s[l][y] = tmp[(size_t)(((b*NNN + l)*4 + h)*DHB + d)*DHB + y];
    }
    for (int idx = tid; idx < NNN*DHB; idx += 256) {
        int k = idx / DHB, y = idx % DHB;
        tt_s[y][k] = ts[(b*NNN + k)*200 + h*DHB + y];
    }
    __syncthreads();
    float* out = scores + (size_t)(b*HID + h*DHB + d)*NNN*NNN;
    for (int o = tid; o < NNN*32; o += 256) {
        int l = o / 32, kb = (o % 32) * 4;
        float4 acc = {0.f,0.f,0.f,0.f};
        for (int y = 0; y < DHB; y++) {
            float t = tmp_s[l][y];
            float4 v = *(const float4*)&tt_s[y][kb];
            acc.x += t*v.x; acc.y += t*v.y; acc.z += t*v.z; acc.w += t*v.w;
        }
        *(float4*)&out[l*NNN + kb] = acc;
    }
}

// ======================= proj MFMA + fused LN (wr4 x wc2 split) ===============
// Verified best: 207 us. acc 14 f32x4 = 56 regs; (512,4) only — (512,8)
// spills (round 10), 16-row blocks slower (round 12), biaf2-merge slower (r18).
__global__ __launch_bounds__(512, 4) void k_proj_mfma(
        const float* __restrict__ soft, const ushort* __restrict__ Wpt,
        const float* __restrict__ hsg, const float* __restrict__ tsg,
        const float* __restrict__ ln_g, const float* __restrict__ ln_b,
        const float* __restrict__ alpha_p, ushort* __restrict__ aff_t)
{
    __shared__ __align__(16) char smem[32768];
    ushort* ts_s = (ushort*)smem;              // [64][200] bf16  (25600 B)
    float*  hs_s = (float*)(smem + 25600);     // [200]
    float*  g_s  = (float*)(smem + 26400);     // [402]
    float*  bb_s = (float*)(smem + 28008);     // [402]
    float*  lnred= (float*)(smem + 29616);     // [2 wc][64 r][2]

    int tid = threadIdx.x;
    int lane = tid & 63, w = tid >> 6;         // w 0..7
    int wr = w >> 1, wc = w & 1;               // wr 0..3 (16 rows), wc 0..1 (224 cols)
    int l15 = lane & 15, kg = lane >> 4;
    int flat0 = blockIdx.x * 64;
    int b  = flat0 >> 14;
    int m  = (flat0 >> 7) & 127;
    int nb = flat0 & 127;

    f32x4 acc[14];
    #pragma unroll
    for (int cf = 0; cf < 14; cf++) acc[cf] = (f32x4){0.f,0.f,0.f,0.f};

    const float* aBase = soft + (size_t)(flat0 + wr*16 + l15)*EMB + kg*8;
    const s16x8* Bp = (const s16x8*)Wpt;
    int bcol = wc*224 + l15;

    #pragma unroll 2
    for (int t = 0; t < 24; t++) {
        float4 f0 = *(const float4*)(aBase + t*32);
        float4 f1 = *(const float4*)(aBase + t*32 + 4);
        s16x8 af = cvt8(f0, f1);
        #pragma unroll
        for (int cf = 0; cf < 14; cf++) {
            s16x8 bfv = Bp[(size_t)t*1792 + kg*448 + bcol + cf*16];
            acc[cf] = __builtin_amdgcn_mfma_f32_16x16x32_bf16(af, bfv, acc[cf], 0, 0, 0);
        }
    }

    // ---- epilogue: add concat, LayerNorm over 402, write bf16 tiled ----
    for (int idx = tid; idx < 64*200; idx += 512) {
        int r = idx / 200, c2 = idx % 200;
        ts_s[r*200 + c2] = f2bf(tsg[((size_t)(b*NNN + nb + r))*200 + c2]);
    }
    for (int idx = tid; idx < 200; idx += 512) hs_s[idx] = hsg[((size_t)(b*NNN + m))*200 + idx];
    for (int idx = tid; idx < HSZ; idx += 512) { g_s[idx] = ln_g[idx]; bb_s[idx] = ln_b[idx]; }
    __syncthreads();

    float alpha = alpha_p[0];
    #pragma unroll
    for (int i = 0; i < 4; i++) {
        int r = wr*16 + ((lane>>4)<<2) + i;
        float s1 = 0.f, s2 = 0.f;
        #pragma unroll
        for (int cf = 0; cf < 14; cf++) {
            int j = wc*224 + cf*16 + l15;
            float v = 0.f;
            if (j < HSZ) {
                float cat;
                if (j < 200)       cat = hs_s[j];
                else if (j == 200) cat = 1.0f;
                else if (j < 401)  cat = bf2f(ts_s[r*200 + (j-201)]);
                else               cat = 1.0f;
                v = cat + alpha*acc[cf][i];
            }
            acc[cf][i] = v;
            s1 += v; s2 += v*v;
        }
        #pragma unroll
        for (int off = 1; off < 16; off <<= 1) {
            s1 += __shfl_xor(s1, off); s2 += __shfl_xor(s2, off);
        }
        if (l15 == 0) {
            lnred[(wc*64 + r)*2 + 0] = s1;
            lnred[(wc*64 + r)*2 + 1] = s2;
        }
    }
    __syncthreads();
    #pragma unroll
    for (int i = 0; i < 4; i++) {
        int r = wr*16 + ((lane>>4)<<2) + i;
        float S1 = lnred[(0*64 + r)*2 + 0] + lnred[(1*64 + r)*2 + 0];
        float S2 = lnred[(0*64 + r)*2 + 1] + lnred[(1*64 + r)*2 + 1];
        float mean = S1 * (1.0f/402.0f);
        float var  = S2 * (1.0f/402.0f) - mean*mean;
        float rinv = rsqrtf(var + 1e-5f);
        int rowglob = flat0 + r;
        int rowblock = rowglob >> 7, rlocal = rowglob & 127;
        #pragma unroll
        for (int cf = 0; cf < 14; cf++) {
            int j = wc*224 + cf*16 + l15;
            if (j < 416) {
                float outv = 0.f;
                if (j < HSZ) outv = g_s[j]*(acc[cf][i] - mean)*rinv + bb_s[j];
                int tile = j >> 5, kg2 = (j >> 3) & 3, jj = j & 7;
                aff_t[(((size_t)rowblock*13 + tile)*512 + kg2*128 + rlocal)*8 + jj] = f2bf(outv);
            }
        }
    }
}

// ======================= W_big MFMA (barrier-free, LDS-free) ==================
__global__ __launch_bounds__(256) void k_wbig_mfma(const ushort* __restrict__ aff_t,
        const ushort* __restrict__ Wbt, float* __restrict__ scores)
{
    int tid = threadIdx.x, lane = tid & 63, w = tid >> 6;
    int l15 = lane & 15, kg = lane >> 4;
    int flat0 = blockIdx.x * 128;
    int b = flat0 >> 14, local0 = flat0 & 16383;
    int rowblock = blockIdx.x;

    f32x4 acc[2][13];
    #pragma unroll
    for (int rf = 0; rf < 2; rf++)
        #pragma unroll
        for (int cf = 0; cf < 13; cf++) acc[rf][cf] = (f32x4){0.f,0.f,0.f,0.f};

    #pragma unroll 2
    for (int t = 0; t < 13; t++) {
        const s16x8* at = (const s16x8*)(aff_t + ((size_t)rowblock*13 + t)*4096);
        s16x8 af[2];
        #pragma unroll
        for (int rf = 0; rf < 2; rf++)
            af[rf] = at[kg*128 + w*32 + rf*16 + l15];
        const s16x8* btp = (const s16x8*)(Wbt + (size_t)t*6656);
        #pragma unroll
        for (int cf = 0; cf < 13; cf++) {
            s16x8 bfv = btp[kg*208 + cf*16 + l15];
            #pragma unroll
            for (int rf = 0; rf < 2; rf++)
                acc[rf][cf] = __builtin_amdgcn_mfma_f32_16x16x32_bf16(af[rf], bfv, acc[rf][cf], 0, 0, 0);
        }
    }
    #pragma unroll
    for (int cf = 0; cf < 13; cf++) {
        int ch = cf*16 + l15;
        if (ch < HID) {
            #pragma unroll
            for (int rf = 0; rf < 2; rf++) {
                size_t base = ((size_t)(b*HID + ch))*16384 + local0 + w*32 + rf*16 + ((lane>>4)<<2);
                float4 old = *(float4*)(scores + base);
                old.x += acc[rf][cf][0]; old.y += acc[rf][cf][1];
                old.z += acc[rf][cf][2]; old.w += acc[rf][cf][3];
                *(float4*)(scores + base) = old;
            }
        }
    }
}

// ======================= gather + qkv(layer0) fused ===========================
__global__ __launch_bounds__(768) void k_gather_qkv(const float* __restrict__ scores,
        const int* __restrict__ id2lr, float* __restrict__ feat,
        const ushort* __restrict__ Wlayer, const float* __restrict__ bq,
        const float* __restrict__ bk, const float* __restrict__ bv,
        float* __restrict__ q, ushort* __restrict__ kf16, ushort* __restrict__ vf16)
{
    __shared__ float tile[64][204];
    int tid = threadIdx.x;
    {
        int sl = tid & 63, cq = tid >> 6;        // cq 0..11
        int gs = blockIdx.x*64 + sl;
        int b = gs / SS;
        int l = id2lr[gs*2 + 0];
        int r = id2lr[gs*2 + 1];
        size_t base = (size_t)b*HID*16384 + l*128 + r;
        for (int c = cq; c < 200; c += 12)
            tile[sl][c] = scores[base + (size_t)c*16384];
    }
    __syncthreads();
    size_t fbase = (size_t)blockIdx.x*64*200;
    for (int idx = tid; idx < 64*200; idx += 768)
        feat[fbase + idx] = tile[idx/200][idx%200];

    int lane = tid & 63, w = tid >> 6;           // w 0..11
    int which = w >> 2, rq = w & 3;
    int l15 = lane & 15, kg = lane >> 4;
    const ushort* Bt = Wlayer + (size_t)which*46592;
    const float* bias = which == 0 ? bq : (which == 1 ? bk : bv);
    f32x4 acc[13];
    #pragma unroll
    for (int cf = 0; cf < 13; cf++) acc[cf] = (f32x4){0.f,0.f,0.f,0.f};
    int arow = rq*16 + l15;
    #pragma unroll
    for (int t = 0; t < 7; t++) {
        int k0 = t*32 + kg*8;
        s16x8 af = (s16x8){0,0,0,0,0,0,0,0};
        if (k0 + 8 <= 200) {
            float4 f0 = *(const float4*)&tile[arow][k0];
            float4 f1 = *(const float4*)&tile[arow][k0 + 4];
            af = cvt8(f0, f1);
        }
        const s16x8* btp = (const s16x8*)(Bt + (size_t)t*6656);
        #pragma unroll
        for (int cf = 0; cf < 13; cf++)
            acc[cf] = __builtin_amdgcn_mfma_f32_16x16x32_bf16(af, btp[kg*208 + cf*16 + l15], acc[cf], 0, 0, 0);
    }
    if (which == 0) {
        #pragma unroll
        for (int cf = 0; cf < 13; cf++) {
            int col = cf*16 + l15;
            if (col < 200) {
                float bi = bias[col];
                #pragma unroll
                for (int i = 0; i < 4; i++) {
                    int row = blockIdx.x*64 + rq*16 + ((lane>>4)<<2) + i;
                    q[(size_t)row*200 + col] = acc[cf][i] + bi;
                }
            }
        }
    } else {
        ushort* out16 = (which == 1) ? kf16 : vf16;
        #pragma unroll
        for (int cf = 0; cf < 13; cf++) {
            int col = cf*16 + l15;
            if (col < 200) {
                float bi = bias[col];
                #pragma unroll
                for (int i = 0; i < 4; i++) {
                    int row = blockIdx.x*64 + rq*16 + ((lane>>4)<<2) + i;
                    out16[(size_t)row*200 + col] = f2bf(acc[cf][i] + bi);
                }
            }
        }
    }
}

// ======================= qkv MFMA (layers 1,2; 2 waves/block) =================
__global__ __launch_bounds__(128) void k_qkv_mfma(const float* __restrict__ feat,
        const ushort* __restrict__ Wlayer, const float* __restrict__ bq,
        const float* __restrict__ bk, const float* __restrict__ bv,
        float* __restrict__ q, ushort* __restrict__ kf16, ushort* __restrict__ vf16)
{
    int bid = blockIdx.x;
    int which = bid % 3, mb = bid / 3;
    const ushort* Bt = Wlayer + (size_t)which*46592;
    const float* bias = which == 0 ? bq : (which == 1 ? bk : bv);
    int tid = threadIdx.x, lane = tid & 63, w = tid >> 6;   // w 0..1
    int l15 = lane & 15, kg = lane >> 4;
    int row0 = mb*32;
    const float* aRow = feat + (size_t)(row0 + w*16 + l15)*200;
    f32x4 acc[13];
    #pragma unroll
    for (int cf = 0; cf < 13; cf++) acc[cf] = (f32x4){0.f,0.f,0.f,0.f};
    #pragma unroll
    for (int t = 0; t < 7; t++) {
        int k0 = t*32 + kg*8;
        s16x8 af = (s16x8){0,0,0,0,0,0,0,0};
        if (k0 + 8 <= 200) {
            float4 f0 = *(const float4*)(aRow + k0);
            float4 f1 = *(const float4*)(aRow + k0 + 4);
            af = cvt8(f0, f1);
        }
        const s16x8* btp = (const s16x8*)(Bt + (size_t)t*6656);
        #pragma unroll
        for (int cf = 0; cf < 13; cf++)
            acc[cf] = __builtin_amdgcn_mfma_f32_16x16x32_bf16(af, btp[kg*208 + cf*16 + l15], acc[cf], 0, 0, 0);
    }
    if (which == 0) {
        #pragma unroll
        for (int cf = 0; cf < 13; cf++) {
            int col = cf*16 + l15;
            if (col < 200) {
                float bi = bias[col];
                #pragma unroll
                for (int i = 0; i < 4; i++) {
                    int row = row0 + w*16 + ((lane>>4)<<2) + i;
                    q[(size_t)row*200 + col] = acc[cf][i] + bi;
                }
            }
        }
    } else {
        ushort* out16 = (which == 1) ? kf16 : vf16;
        #pragma unroll
        for (int cf = 0; cf < 13; cf++) {
            int col = cf*16 + l15;
            if (col < 200) {
                float bi = bias[col];
                #pragma unroll
                for (int i = 0; i < 4; i++) {
                    int row = row0 + w*16 + ((lane>>4)<<2) + i;
                    out16[(size_t)row*200 + col] = f2bf(acc[cf][i] + bi);
                }
            }
        }
    }
}

// ======================= attention core (1 span / 1-wave block, bf16 K/V) =====
// opre now stored bf16 (consumed as MFMA A-operand in oln anyway).
__global__ __launch_bounds__(64) void k_attn(const float* __restrict__ q,
        const ushort* __restrict__ kf16, const ushort* __restrict__ vf16,
        const int* __restrict__ N_idx, const float* __restrict__ head_gate,
        ushort* __restrict__ opre16) {
    int rowg = blockIdx.x;          // b*3600+s
    int b = rowg / SS, s = rowg % SS;
    __shared__ float Kb[KKK][200];
    __shared__ float qs[200];
    __shared__ float lgs[40];
    __shared__ float at[4][KKK];
    __shared__ int idxs[KKK];
    int lane = threadIdx.x;
    if (lane < KKK) idxs[lane] = N_idx[rowg*KKK + lane];
    if (lane < 50) ((float4*)qs)[lane] = ((const float4*)(q + (size_t)rowg*200))[lane];
    __syncthreads();
    for (int i = lane; i < KKK*50; i += 64) {
        int k = i / 50, c = i % 50;
        int nb = idxs[k];
        ushort4 uv = *(const ushort4*)&kf16[((size_t)(b*SS) + nb)*200 + c*4];
        Kb[k][c*4+0] = bf2f(uv.x); Kb[k][c*4+1] = bf2f(uv.y);
        Kb[k][c*4+2] = bf2f(uv.z); Kb[k][c*4+3] = bf2f(uv.w);
    }
    __syncthreads();
    if (lane < 40) {
        int h = lane / KKK, k = lane % KKK;
        float acc = 0.f;
        #pragma unroll 10
        for (int d = 0; d < DHB; d++) acc += qs[h*DHB + d]*Kb[k][h*DHB + d];
        lgs[lane] = acc*0.141421356237309515f
                  + logf(head_gate[((size_t)(b*4 + h)*SS + s)*KKK + k] + 1e-9f);
    }
    __syncthreads();
    if (lane < 4) {
        int h = lane;
        float mx = -1e30f;
        for (int k = 0; k < KKK; k++) mx = fmaxf(mx, lgs[h*KKK + k]);
        float sum = 0.f;
        float e[KKK];
        for (int k = 0; k < KKK; k++) { e[k] = expf(lgs[h*KKK + k] - mx); sum += e[k]; }
        float inv = 1.f/sum;
        for (int k = 0; k < KKK; k++) at[h][k] = e[k]*inv;
    }
    __syncthreads();
    if (lane < 50) {
        int c0 = lane*4;
        int ha = c0/DHB, hb = (c0+1)/DHB, hc = (c0+2)/DHB, hd = (c0+3)/DHB;
        float o0=0.f, o1=0.f, o2=0.f, o3=0.f;
        #pragma unroll
        for (int k = 0; k < KKK; k++) {
            ushort4 uv = *(const ushort4*)&vf16[((size_t)(b*SS) + idxs[k])*200 + c0];
            o0 += at[ha][k]*bf2f(uv.x); o1 += at[hb][k]*bf2f(uv.y);
            o2 += at[hc][k]*bf2f(uv.z); o3 += at[hd][k]*bf2f(uv.w);
        }
        ushort4 ov;
        ov.x = f2bf(o0); ov.y = f2bf(o1); ov.z = f2bf(o2); ov.w = f2bf(o3);
        *(ushort4*)&opre16[(size_t)rowg*200 + c0] = ov;
    }
}

// ======================= o@Wo + residual + LN (2 waves/block, 32 rows) ========
// A-operand read directly as bf16 from opre16 (no cvt).
__global__ __launch_bounds__(128) void k_oln_mfma(const ushort* __restrict__ opre16,
        const ushort* __restrict__ Wot, const float* __restrict__ bo,
        const float* __restrict__ lngp, const float* __restrict__ lnbp,
        float* __restrict__ feat)
{
    int tid = threadIdx.x, lane = tid & 63, w = tid >> 6;   // w 0..1
    int l15 = lane & 15, kg = lane >> 4;
    int row0 = blockIdx.x*32;
    const ushort* aRow = opre16 + (size_t)(row0 + w*16 + l15)*200;
    f32x4 acc[13];
    #pragma unroll
    for (int cf = 0; cf < 13; cf++) acc[cf] = (f32x4){0.f,0.f,0.f,0.f};
    #pragma unroll
    for (int t = 0; t < 7; t++) {
        int k0 = t*32 + kg*8;
        s16x8 af = (s16x8){0,0,0,0,0,0,0,0};
        if (k0 + 8 <= 200) af = *(const s16x8*)(aRow + k0);
        const s16x8* btp = (const s16x8*)(Wot + (size_t)t*6656);
        #pragma unroll
        for (int cf = 0; cf < 13; cf++)
            acc[cf] = __builtin_amdgcn_mfma_f32_16x16x32_bf16(af, btp[kg*208 + cf*16 + l15], acc[cf], 0, 0, 0);
    }
    #pragma unroll
    for (int i = 0; i < 4; i++) {
        int row = row0 + w*16 + ((lane>>4)<<2) + i;
        float xv[13];
        float s1 = 0.f, s2 = 0.f;
        #pragma unroll
        for (int cf = 0; cf < 13; cf++) {
            int col = cf*16 + l15;
            float x = 0.f;
            if (col < 200) x = feat[(size_t)row*200 + col] + acc[cf][i] + bo[col];
            xv[cf] = x; s1 += x; s2 += x*x;
        }
        #pragma unroll
        for (int off = 1; off < 16; off <<= 1) {
            s1 += __shfl_xor(s1, off); s2 += __shfl_xor(s2, off);
        }
        float mean = s1*(1.0f/200.0f);
        float var  = s2*(1.0f/200.0f) - mean*mean;
        float rinv = rsqrtf(var + 1e-5f);
        #pragma unroll
        for (int cf = 0; cf < 13; cf++) {
            int col = cf*16 + l15;
            if (col < 200)
                feat[(size_t)row*200 + col] = lngp[col]*(xv[cf] - mean)*rinv + lnbp[col];
        }
    }
}

// ======================= scatter (span-major, 450 x 128) ======================
__global__ __launch_bounds__(128) void k_scatter(const float* __restrict__ feat,
        const int* __restrict__ id2lr, float* __restrict__ scores) {
    __shared__ float tile[32][201];
    int tid = threadIdx.x;
    size_t fbase = (size_t)blockIdx.x*32*200;
    for (int idx = tid; idx < 32*200; idx += 128)
        tile[idx/200][idx%200] = feat[fbase + idx];
    __syncthreads();
    int sl = tid & 31, cq = tid >> 5;    // cq 0..3
    int gs = blockIdx.x*32 + sl;
    int b = gs / SS;
    int l = id2lr[gs*2 + 0];
    int r = id2lr[gs*2 + 1];
    size_t base = (size_t)b*HID*16384 + l*128 + r;
    for (int c = cq; c < 200; c += 4)
        scores[base + (size_t)c*16384] = tile[sl][c];
}

// ======================= down-projection (2-way c-split, 256 thr) =============
__global__ __launch_bounds__(256) void k_down(const float* __restrict__ scores,
        const float* __restrict__ Wd, const float* __restrict__ bd,
        float* __restrict__ out) {
    __shared__ float wd[200][9];
    __shared__ float bds[9];
    __shared__ float part[128][9];
    int tid = threadIdx.x;
    for (int idx = tid; idx < 1800; idx += 256) wd[idx/9][idx%9] = Wd[idx];
    if (tid < 9) bds[tid] = bd[tid];
    __syncthreads();
    int bm = blockIdx.x;
    int b = bm / NNN, m = bm % NNN;
    int g = tid >> 7, n = tid & 127;
    float acc[9];
    #pragma unroll
    for (int k = 0; k < 9; k++) acc[k] = 0.f;
    for (int c = g*100; c < g*100 + 100; c++) {
        float sv = scores[((size_t)(b*HID + c)*NNN + m)*NNN + n];
        #pragma unroll
        for (int k = 0; k < 9; k++) acc[k] += sv*wd[c][k];
    }
    if (g == 1) {
        #pragma unroll
        for (int k = 0; k < 9; k++) part[n][k] = acc[k];
    }
    __syncthreads();
    if (g == 0) {
        #pragma unroll
        for (int k = 0; k < 9; k++)
            out[((size_t)bm*NNN + n)*9 + k] = acc[k] + part[n][k] + bds[k];
    }
}

extern "C" void kernel_launch(void* const* d_in, const int* in_sizes, int n_in,
                              void* d_out, int out_size, void* d_ws, size_t ws_size,
                              hipStream_t stream) {
    (void)in_sizes; (void)n_in; (void)out_size; (void)ws_size;
    const float* word  = (const float*)d_in[0];
    const float* soft  = (const float*)d_in[1];
    const float* hgate = (const float*)d_in[2];
    const int*   N_idx = (const int*)d_in[3];
    const int*   id2lr = (const int*)d_in[5];
    const float* Wh = (const float*)d_in[7];  const float* bh = (const float*)d_in[8];
    const float* Wt = (const float*)d_in[9];  const float* bt = (const float*)d_in[10];
    const float* U  = (const float*)d_in[11];
    const float* Wbig = (const float*)d_in[12];
    const float* Wp = (const float*)d_in[13];
    const float* lng_a = (const float*)d_in[14]; const float* lnb_a = (const float*)d_in[15];
    const float* alpha = (const float*)d_in[16];
    const float* Wq = (const float*)d_in[17]; const float* bq = (const float*)d_in[18];
    const float* Wk = (const float*)d_in[19]; const float* bk = (const float*)d_in[20];
    const float* Wv = (const float*)d_in[21]; const float* bv = (const float*)d_in[22];
    const float* Wo = (const float*)d_in[23]; const float* bo = (const float*)d_in[24];
    const float* lng = (const float*)d_in[25]; const float* lnb = (const float*)d_in[26];
    const float* Wd = (const float*)d_in[27]; const float* bd = (const float*)d_in[28];

    float* ws = (float*)d_ws;
    float* hs     = ws;
    float* tsb    = hs + 102400;
    float* scores = tsb + 102400;
    ushort* Wpt     = (ushort*)(scores + 13107200);
    ushort* Wbt     = Wpt + 344064;
    ushort* word_bf = Wbt + 86528;
    ushort* whht_bf = word_bf + 393216;
    ushort* wall_bf = whht_bf + 319488;
    float* big    = ws + 14163200;
    float* tmp    = big;
    ushort* aff_t = (ushort*)big;
    float* feat   = big;
    float* qb     = big + 2880000;
    ushort* kf16  = (ushort*)(big + 5760000);
    ushort* vf16  = (ushort*)(big + 8640000);
    ushort* opre16= (ushort*)(big + 11520000);

    k_cvt_all<<<6650, 256, 0, stream>>>(word, Wh, Wt, Wq, Wk, Wv, Wo, Wp, Wbig,
                                        word_bf, whht_bf, wall_bf, Wpt, Wbt);

    k_hsts_mfma<<<832, 64, 0, stream>>>(word_bf, whht_bf, bh, bt, hs, tsb);
    k_biaf1<<<256, 256, 0, stream>>>(hs, U, tmp);
    k_biaf2<<<800, 256, 0, stream>>>(tmp, tsb, scores);
    k_proj_mfma<<<1024, 512, 0, stream>>>(soft, Wpt, hs, tsb, lng_a, lnb_a, alpha, aff_t);
    k_wbig_mfma<<<512, 256, 0, stream>>>(aff_t, Wbt, scores);
    k_gather_qkv<<<225, 768, 0, stream>>>(scores, id2lr, feat, wall_bf,
                                          bq, bk, bv, qb, kf16, vf16);
    for (int i = 0; i < 3; i++) {
        k_attn<<<14400, 64, 0, stream>>>(qb, kf16, vf16, N_idx, hgate, opre16);
        k_oln_mfma<<<450, 128, 0, stream>>>(opre16, wall_bf + (size_t)(i*4+3)*46592,
                                            bo + i*200, lng + i*200, lnb + i*200, feat);
        if (i < 2)
            k_qkv_mfma<<<1350, 128, 0, stream>>>(feat, wall_bf + (size_t)(i+1)*4*46592,
                                                 bq + (i+1)*200, bk + (i+1)*200, bv + (i+1)*200,
                                                 qb, kf16, vf16);
    }
    k_scatter<<<450, 128, 0, stream>>>(feat, id2lr, scores);
    k_down<<<512, 256, 0, stream>>>(scores, Wd, bd, (float*)d_out);
}